// Round 1
// baseline (1458.637 us; speedup 1.0000x reference)
//
#include <hip/hip_runtime.h>

#define N0c 524288
#define N1c 131072
#define Bc  512
#define Dc  128
#define Hc  128
#define Cc  10
#define EPSc 1e-5f

// ---------------------------------------------------------------------------
// Scatter + project kernel. Processes rows of src [nrows][128].
// If scale != nullptr, applies y = relu(x*scale + shift) first (BN+ReLU).
// Scatters row y into dstP[idxP[r]][:] via fp32 atomics, and accumulates
// y . predW[wrow0 .. wrow0+127][0..9] into accG[idxT[r]][0..9] (LDS-staged).
// ---------------------------------------------------------------------------
__global__ __launch_bounds__(256) void k_scatter(
    const float* __restrict__ src, const int* __restrict__ idxP,
    const int* __restrict__ idxT, const float* __restrict__ predW, int wrow0,
    const float* __restrict__ scale, const float* __restrict__ shift,
    float* __restrict__ dstP, float* __restrict__ accG, int nrows)
{
    __shared__ float wl[Dc * Cc];     // 1280 floats
    __shared__ float accl[Bc * Cc];   // 5120 floats
    __shared__ float scl[Dc], shl[Dc];

    const int tid = threadIdx.x;
    for (int i = tid; i < Dc * Cc; i += 256) wl[i] = predW[wrow0 * Cc + i];
    for (int i = tid; i < Bc * Cc; i += 256) accl[i] = 0.f;
    if (scale != nullptr && tid < Dc) { scl[tid] = scale[tid]; shl[tid] = shift[tid]; }
    __syncthreads();

    const int sub = tid >> 5;     // 0..7 row within 8-row group
    const int lane = tid & 31;    // 32 lanes per row, float4 each
    const bool bn = (scale != nullptr);

    for (int base = blockIdx.x * 8; base < nrows; base += gridDim.x * 8) {
        int r = base + sub;
        if (r >= nrows) break;
        float4 v = ((const float4*)(src + (size_t)r * Dc))[lane];
        if (bn) {
            v.x = fmaxf(v.x * scl[lane*4+0] + shl[lane*4+0], 0.f);
            v.y = fmaxf(v.y * scl[lane*4+1] + shl[lane*4+1], 0.f);
            v.z = fmaxf(v.z * scl[lane*4+2] + shl[lane*4+2], 0.f);
            v.w = fmaxf(v.w * scl[lane*4+3] + shl[lane*4+3], 0.f);
        }
        int par = idxP[r];
        int tr  = idxT[r];
        float* dst = dstP + (size_t)par * Dc + lane * 4;
        atomicAdd(dst + 0, v.x);
        atomicAdd(dst + 1, v.y);
        atomicAdd(dst + 2, v.z);
        atomicAdd(dst + 3, v.w);

        float pv[Cc];
        #pragma unroll
        for (int c = 0; c < Cc; c++) {
            pv[c] = v.x * wl[(lane*4+0)*Cc + c]
                  + v.y * wl[(lane*4+1)*Cc + c]
                  + v.z * wl[(lane*4+2)*Cc + c]
                  + v.w * wl[(lane*4+3)*Cc + c];
        }
        #pragma unroll
        for (int off = 16; off; off >>= 1) {
            #pragma unroll
            for (int c = 0; c < Cc; c++) pv[c] += __shfl_xor(pv[c], off, 32);
        }
        if (lane == 0) {
            #pragma unroll
            for (int c = 0; c < Cc; c++) atomicAdd(&accl[tr * Cc + c], pv[c]);
        }
    }
    __syncthreads();
    for (int i = tid; i < Bc * Cc; i += 256) atomicAdd(&accG[i], accl[i]);
}

// ---------------------------------------------------------------------------
// GEMM: out[M][128] = f(in[M][128]) @ W[128][128] + bias, where f is identity
// or relu(x*scale+shift) (BN+ReLU applied on load). Also accumulates per-column
// sum and sum-of-squares of OUT into ssum/ssq (for the next BN's batch stats).
// Block: 256 threads, tile 32 rows x 128 cols, thread tile 4x4. in==out is
// safe (rows staged in LDS before overwrite).
// ---------------------------------------------------------------------------
__global__ __launch_bounds__(256) void k_gemm(
    const float* __restrict__ in, float* __restrict__ out,
    const float* __restrict__ W, const float* __restrict__ bias,
    const float* __restrict__ scale, const float* __restrict__ shift,
    float* __restrict__ ssum, float* __restrict__ ssq, int M)
{
    __shared__ float Wl[Hc * Hc];    // 64 KB
    __shared__ float inl[32 * Hc];   // 16 KB (reused as reduction scratch)

    const int tid = threadIdx.x;
    {
        const float4* W4 = (const float4*)W;
        float4* Wl4 = (float4*)Wl;
        for (int i = tid; i < Hc * Hc / 4; i += 256) Wl4[i] = W4[i];
    }
    const int row0 = blockIdx.x * 32;
    const bool bn = (scale != nullptr);
    for (int i = tid; i < 32 * 32; i += 256) {
        int r = i >> 5, g = i & 31;
        float4 v = ((const float4*)(in + (size_t)(row0 + r) * Hc))[g];
        if (bn) {
            float4 sc = ((const float4*)scale)[g];
            float4 sh = ((const float4*)shift)[g];
            v.x = fmaxf(v.x * sc.x + sh.x, 0.f);
            v.y = fmaxf(v.y * sc.y + sh.y, 0.f);
            v.z = fmaxf(v.z * sc.z + sh.z, 0.f);
            v.w = fmaxf(v.w * sc.w + sh.w, 0.f);
        }
        ((float4*)(inl + r * Hc))[g] = v;
    }
    __syncthreads();

    const int rg = tid >> 5;   // 0..7  -> rows rg*4..rg*4+3
    const int cg = tid & 31;   // 0..31 -> cols cg*4..cg*4+3
    float acc[4][4] = {{0.f}};
    for (int k = 0; k < Hc; k += 4) {
        float a[4][4], w[4][4];
        #pragma unroll
        for (int r = 0; r < 4; r++) {
            float4 t = *(const float4*)&inl[(rg*4 + r) * Hc + k];
            a[r][0] = t.x; a[r][1] = t.y; a[r][2] = t.z; a[r][3] = t.w;
        }
        #pragma unroll
        for (int kk = 0; kk < 4; kk++) {
            float4 t = *(const float4*)&Wl[(k + kk) * Hc + cg*4];
            w[kk][0] = t.x; w[kk][1] = t.y; w[kk][2] = t.z; w[kk][3] = t.w;
        }
        #pragma unroll
        for (int r = 0; r < 4; r++)
            #pragma unroll
            for (int kk = 0; kk < 4; kk++)
                #pragma unroll
                for (int c = 0; c < 4; c++)
                    acc[r][c] = fmaf(a[r][kk], w[kk][c], acc[r][c]);
    }

    float b4[4];
    #pragma unroll
    for (int c = 0; c < 4; c++) b4[c] = bias[cg*4 + c];
    float s[4] = {0.f,0.f,0.f,0.f}, q[4] = {0.f,0.f,0.f,0.f};
    #pragma unroll
    for (int r = 0; r < 4; r++) {
        float4 o;
        float v0 = acc[r][0] + b4[0];
        float v1 = acc[r][1] + b4[1];
        float v2 = acc[r][2] + b4[2];
        float v3 = acc[r][3] + b4[3];
        o.x = v0; o.y = v1; o.z = v2; o.w = v3;
        s[0] += v0; s[1] += v1; s[2] += v2; s[3] += v3;
        q[0] += v0*v0; q[1] += v1*v1; q[2] += v2*v2; q[3] += v3*v3;
        *(float4*)&out[(size_t)(row0 + rg*4 + r) * Hc + cg*4] = o;
    }

    __syncthreads();   // inl free now
    #pragma unroll
    for (int c = 0; c < 4; c++) inl[rg * Hc + cg*4 + c] = s[c];
    __syncthreads();
    if (tid < Hc) {
        float t = 0.f;
        #pragma unroll
        for (int g = 0; g < 8; g++) t += inl[g * Hc + tid];
        atomicAdd(&ssum[tid], t);
    }
    __syncthreads();
    #pragma unroll
    for (int c = 0; c < 4; c++) inl[rg * Hc + cg*4 + c] = q[c];
    __syncthreads();
    if (tid < Hc) {
        float t = 0.f;
        #pragma unroll
        for (int g = 0; g < 8; g++) t += inl[g * Hc + tid];
        atomicAdd(&ssq[tid], t);
    }
}

// ---------------------------------------------------------------------------
// BN stat finalize: scale = g * rsqrt(var+eps), shift = b - mean*scale.
// ---------------------------------------------------------------------------
__global__ __launch_bounds__(128) void k_fin(
    const float* __restrict__ sum, const float* __restrict__ sq,
    const float* __restrict__ g, const float* __restrict__ b,
    float* __restrict__ scale, float* __restrict__ shift, float invN)
{
    int t = threadIdx.x;
    float m = sum[t] * invN;
    float v = sq[t] * invN - m * m;
    float s = g[t] * rsqrtf(v + EPSc);
    scale[t] = s;
    shift[t] = b[t] - m * s;
}

// ---------------------------------------------------------------------------
// Final: h2 = relu(bnD(u2)); logits = acc0 + acc1 + h2 @ predW[256:384] + pb;
// softmax. One block per tree.
// ---------------------------------------------------------------------------
__global__ __launch_bounds__(128) void k_final(
    const float* __restrict__ u2, const float* __restrict__ scaleD,
    const float* __restrict__ shiftD, const float* __restrict__ acc0,
    const float* __restrict__ acc1, const float* __restrict__ predW,
    const float* __restrict__ predb, float* __restrict__ out)
{
    __shared__ float h[Hc];
    __shared__ float wl[Hc * Cc];
    __shared__ float lg[Cc], ex[Cc];
    int b = blockIdx.x, t = threadIdx.x;
    for (int i = t; i < Hc * Cc; i += 128) wl[i] = predW[(2*Hc) * Cc + i];
    float x = u2[(size_t)b * Hc + t];
    h[t] = fmaxf(x * scaleD[t] + shiftD[t], 0.f);
    __syncthreads();
    if (t < Cc) {
        float s = predb[t] + acc0[b * Cc + t] + acc1[b * Cc + t];
        for (int d = 0; d < Hc; d++) s += h[d] * wl[d * Cc + t];
        lg[t] = s;
    }
    __syncthreads();
    if (t < Cc) {
        float m = lg[0];
        #pragma unroll
        for (int c = 1; c < Cc; c++) m = fmaxf(m, lg[c]);
        ex[t] = expf(lg[t] - m);
    }
    __syncthreads();
    if (t < Cc) {
        float s = 0.f;
        #pragma unroll
        for (int c = 0; c < Cc; c++) s += ex[c];
        out[b * Cc + t] = ex[t] / s;
    }
}

extern "C" void kernel_launch(void* const* d_in, const int* in_sizes, int n_in,
                              void* d_out, int out_size, void* d_ws, size_t ws_size,
                              hipStream_t stream) {
    const float* h0      = (const float*)d_in[0];
    const int*   parent1 = (const int*)d_in[1];
    const int*   parent2 = (const int*)d_in[2];
    const int*   tree0   = (const int*)d_in[3];
    const int*   tree1   = (const int*)d_in[4];
    const float* m1W1 = (const float*)d_in[5];
    const float* m1b1 = (const float*)d_in[6];
    const float* m1bng = (const float*)d_in[7];
    const float* m1bnb = (const float*)d_in[8];
    const float* m1W2 = (const float*)d_in[9];
    const float* m1b2 = (const float*)d_in[10];
    const float* bn1g = (const float*)d_in[11];
    const float* bn1b = (const float*)d_in[12];
    const float* m2W1 = (const float*)d_in[13];
    const float* m2b1 = (const float*)d_in[14];
    const float* m2bng = (const float*)d_in[15];
    const float* m2bnb = (const float*)d_in[16];
    const float* m2W2 = (const float*)d_in[17];
    const float* m2b2 = (const float*)d_in[18];
    const float* bn2g = (const float*)d_in[19];
    const float* bn2b = (const float*)d_in[20];
    const float* predW = (const float*)d_in[21];
    const float* predb = (const float*)d_in[22];
    float* out = (float*)d_out;

    float* ws   = (float*)d_ws;
    float* buf  = ws;                              // N1*128: p1 -> t1 -> t4 (in place)
    float* p2   = ws + (size_t)N1c * Hc;           // 512*128
    float* u1   = p2 + Bc * Hc;                    // 512*128
    float* u2   = u1 + Bc * Hc;                    // 512*128
    float* acc0 = u2 + Bc * Hc;                    // 512*10
    float* acc1 = acc0 + Bc * Cc;                  // 512*10
    float* stats = acc1 + Bc * Cc;                 // 8*128
    float* coeff = stats + 8 * Hc;                 // 8*128
    float* sumA = stats + 0 * Hc; float* sqA = stats + 1 * Hc;
    float* sumB = stats + 2 * Hc; float* sqB = stats + 3 * Hc;
    float* sumC = stats + 4 * Hc; float* sqC = stats + 5 * Hc;
    float* sumD = stats + 6 * Hc; float* sqD = stats + 7 * Hc;
    float* scaleA = coeff + 0 * Hc; float* shiftA = coeff + 1 * Hc;
    float* scaleB = coeff + 2 * Hc; float* shiftB = coeff + 3 * Hc;
    float* scaleC = coeff + 4 * Hc; float* shiftC = coeff + 5 * Hc;
    float* scaleD = coeff + 6 * Hc; float* shiftD = coeff + 7 * Hc;

    // zero accumulation targets
    hipMemsetAsync(buf, 0, (size_t)N1c * Hc * sizeof(float), stream);
    hipMemsetAsync(p2, 0, (size_t)(3 * Bc * Hc + 2 * Bc * Cc + 8 * Hc) * sizeof(float), stream);

    // h0 pass: p1 scatter + g0 projection
    k_scatter<<<512, 256, 0, stream>>>(h0, parent1, tree0, predW, 0,
                                       nullptr, nullptr, buf, acc0, N0c);
    // layer-1 MLP
    k_gemm<<<N1c / 32, 256, 0, stream>>>(buf, buf, m1W1, m1b1, nullptr, nullptr,
                                         sumA, sqA, N1c);
    k_fin<<<1, 128, 0, stream>>>(sumA, sqA, m1bng, m1bnb, scaleA, shiftA, 1.f / N1c);
    k_gemm<<<N1c / 32, 256, 0, stream>>>(buf, buf, m1W2, m1b2, scaleA, shiftA,
                                         sumB, sqB, N1c);
    k_fin<<<1, 128, 0, stream>>>(sumB, sqB, bn1g, bn1b, scaleB, shiftB, 1.f / N1c);
    // h1 pass: p2 scatter + g1 projection (applies bnB+relu on load)
    k_scatter<<<512, 256, 0, stream>>>(buf, parent2, tree1, predW, Hc,
                                       scaleB, shiftB, p2, acc1, N1c);
    // layer-2 MLP (tiny)
    k_gemm<<<Bc / 32, 256, 0, stream>>>(p2, u1, m2W1, m2b1, nullptr, nullptr,
                                        sumC, sqC, Bc);
    k_fin<<<1, 128, 0, stream>>>(sumC, sqC, m2bng, m2bnb, scaleC, shiftC, 1.f / Bc);
    k_gemm<<<Bc / 32, 256, 0, stream>>>(u1, u2, m2W2, m2b2, scaleC, shiftC,
                                        sumD, sqD, Bc);
    k_fin<<<1, 128, 0, stream>>>(sumD, sqD, bn2g, bn2b, scaleD, shiftD, 1.f / Bc);
    // final: h2 + logits + softmax
    k_final<<<Bc, 128, 0, stream>>>(u2, scaleD, shiftD, acc0, acc1, predW, predb, out);
}

// Round 2
// 952.777 us; speedup vs baseline: 1.5309x; 1.5309x over previous
//
#include <hip/hip_runtime.h>

#define N0c 524288
#define N1c 131072
#define Bc  512
#define Dc  128
#define Hc  128
#define Cc  10
#define EPSc 1e-5f

// ---------------------------------------------------------------------------
// Counting-sort machinery: histogram -> 2-level exclusive scan -> place.
// ---------------------------------------------------------------------------
__global__ __launch_bounds__(256) void k_count(const int* __restrict__ idx,
                                               int* __restrict__ cnt, int n)
{
    int r = blockIdx.x * 256 + threadIdx.x;
    if (r < n) atomicAdd(&cnt[idx[r]], 1);
}

__global__ __launch_bounds__(256) void k_scan_local(const int* __restrict__ cnt,
                                                    int* __restrict__ off,
                                                    int* __restrict__ bsum, int n)
{
    __shared__ int s[256];
    int t = threadIdx.x;
    int i = blockIdx.x * 256 + t;
    int v = (i < n) ? cnt[i] : 0;
    s[t] = v; __syncthreads();
    for (int o = 1; o < 256; o <<= 1) {
        int x = (t >= o) ? s[t - o] : 0;
        __syncthreads();
        s[t] += x;
        __syncthreads();
    }
    if (i < n) off[i] = s[t] - v;          // exclusive within block
    if (t == 255) bsum[blockIdx.x] = s[255];
}

__global__ __launch_bounds__(512) void k_scan_sums(int* __restrict__ bsum, int nb)
{
    __shared__ int s[512];
    int t = threadIdx.x;
    int v = (t < nb) ? bsum[t] : 0;
    s[t] = v; __syncthreads();
    for (int o = 1; o < 512; o <<= 1) {
        int x = (t >= o) ? s[t - o] : 0;
        __syncthreads();
        s[t] += x;
        __syncthreads();
    }
    if (t < nb) bsum[t] = s[t] - v;        // exclusive block offsets
}

__global__ __launch_bounds__(256) void k_scan_add(int* __restrict__ off,
                                                  const int* __restrict__ bsum, int n)
{
    int i = blockIdx.x * 256 + threadIdx.x;
    if (i < n) off[i] += bsum[blockIdx.x];
}

__global__ __launch_bounds__(256) void k_place(const int* __restrict__ idx,
                                               const int* __restrict__ off,
                                               int* __restrict__ cur,
                                               int* __restrict__ child, int n)
{
    int r = blockIdx.x * 256 + threadIdx.x;
    if (r < n) {
        int p = idx[r];
        int pos = off[p] + atomicAdd(&cur[p], 1);
        child[pos] = r;
    }
}

// ---------------------------------------------------------------------------
// Gather: for each segment, sum child rows of src [.,128] (optionally applying
// y = relu(x*scale+shift) per row first). Writes segment sums to dstP (plain
// store if chunks==1, atomic partial add if chunks>1). Also projects each
// child row onto predW[wrow0..wrow0+127][0..9] and accumulates per-tree into
// an LDS accumulator, dumped to a per-block slab (merged by k_reduce).
// Block = 512 threads = 16 groups of 32 lanes; group <-> one (segment,chunk).
// ---------------------------------------------------------------------------
__global__ __launch_bounds__(512) void k_gather(
    const float* __restrict__ src, const int* __restrict__ child,
    const int* __restrict__ off, const int* __restrict__ cnt,
    const int* __restrict__ tre, const float* __restrict__ predW, int wrow0,
    const float* __restrict__ scale, const float* __restrict__ shift,
    float* __restrict__ dstP, float* __restrict__ slab,
    int nseg, int chunks)
{
    __shared__ float accl[Bc * Cc];      // 20 KB per-block tree accumulator
    const int tid = threadIdx.x;
    for (int i = tid; i < Bc * Cc; i += 512) accl[i] = 0.f;

    const int lane = tid & 31;
    const int sub  = tid >> 5;           // 0..15

    // per-thread pred_W fragment: wreg[c] = predW rows (wrow0+lane*4 .. +3), col c
    float4 wreg[Cc];
    #pragma unroll
    for (int c = 0; c < Cc; c++) {
        wreg[c].x = predW[(wrow0 + lane * 4 + 0) * Cc + c];
        wreg[c].y = predW[(wrow0 + lane * 4 + 1) * Cc + c];
        wreg[c].z = predW[(wrow0 + lane * 4 + 2) * Cc + c];
        wreg[c].w = predW[(wrow0 + lane * 4 + 3) * Cc + c];
    }
    const bool bn = (scale != nullptr);
    float4 sc4 = make_float4(1.f, 1.f, 1.f, 1.f);
    float4 sh4 = make_float4(0.f, 0.f, 0.f, 0.f);
    if (bn) {
        sc4 = ((const float4*)scale)[lane];
        sh4 = ((const float4*)shift)[lane];
    }
    __syncthreads();

    float4 acc;
    auto process = [&](float4 v, int r) {
        if (bn) {
            v.x = fmaxf(v.x * sc4.x + sh4.x, 0.f);
            v.y = fmaxf(v.y * sc4.y + sh4.y, 0.f);
            v.z = fmaxf(v.z * sc4.z + sh4.z, 0.f);
            v.w = fmaxf(v.w * sc4.w + sh4.w, 0.f);
        }
        acc.x += v.x; acc.y += v.y; acc.z += v.z; acc.w += v.w;
        float pv[Cc];
        #pragma unroll
        for (int c = 0; c < Cc; c++)
            pv[c] = v.x * wreg[c].x + v.y * wreg[c].y
                  + v.z * wreg[c].z + v.w * wreg[c].w;
        #pragma unroll
        for (int o = 16; o; o >>= 1) {
            #pragma unroll
            for (int c = 0; c < Cc; c++) pv[c] += __shfl_xor(pv[c], o, 32);
        }
        if (lane == 0) {
            int tr = tre[r];
            #pragma unroll
            for (int c = 0; c < Cc; c++) atomicAdd(&accl[tr * Cc + c], pv[c]);
        }
    };

    const int G = gridDim.x * 16;
    const int ntask = nseg * chunks;
    for (int t = blockIdx.x * 16 + sub; t < ntask; t += G) {
        int seg = t % nseg;
        int ch  = t / nseg;
        int beg = off[seg], len = cnt[seg];
        int c0 = (int)(((long long)len * ch) / chunks);
        int c1 = (int)(((long long)len * (ch + 1)) / chunks);
        acc = make_float4(0.f, 0.f, 0.f, 0.f);
        int c = c0;
        for (; c + 1 < c1; c += 2) {
            int r0 = child[beg + c], r1 = child[beg + c + 1];
            float4 v0 = ((const float4*)(src + (size_t)r0 * Hc))[lane];
            float4 v1 = ((const float4*)(src + (size_t)r1 * Hc))[lane];
            process(v0, r0);
            process(v1, r1);
        }
        if (c < c1) {
            int r0 = child[beg + c];
            float4 v0 = ((const float4*)(src + (size_t)r0 * Hc))[lane];
            process(v0, r0);
        }
        if (chunks == 1) {
            ((float4*)(dstP + (size_t)seg * Hc))[lane] = acc;
        } else {
            float* d = dstP + (size_t)seg * Hc + lane * 4;
            atomicAdd(d + 0, acc.x);
            atomicAdd(d + 1, acc.y);
            atomicAdd(d + 2, acc.z);
            atomicAdd(d + 3, acc.w);
        }
    }
    __syncthreads();
    for (int i = tid; i < Bc * Cc; i += 512)
        slab[(size_t)blockIdx.x * (Bc * Cc) + i] = accl[i];
}

// slab [rows][5120] column-sum -> out[5120]
__global__ __launch_bounds__(256) void k_reduce(const float* __restrict__ slab,
                                                float* __restrict__ out, int rows)
{
    int i = blockIdx.x * 256 + threadIdx.x;
    if (i < Bc * Cc) {
        float s = 0.f;
        for (int r = 0; r < rows; r++) s += slab[(size_t)r * (Bc * Cc) + i];
        out[i] = s;
    }
}

// ---------------------------------------------------------------------------
// GEMM: out[M][128] = f(in[M][128]) @ W[128][128] + bias, f = identity or
// relu(x*scale+shift). Accumulates column sum/sumsq of OUT into ssum/ssq.
// ---------------------------------------------------------------------------
__global__ __launch_bounds__(256) void k_gemm(
    const float* __restrict__ in, float* __restrict__ out,
    const float* __restrict__ W, const float* __restrict__ bias,
    const float* __restrict__ scale, const float* __restrict__ shift,
    float* __restrict__ ssum, float* __restrict__ ssq, int M)
{
    __shared__ float Wl[Hc * Hc];    // 64 KB
    __shared__ float inl[32 * Hc];   // 16 KB (reused as reduction scratch)

    const int tid = threadIdx.x;
    {
        const float4* W4 = (const float4*)W;
        float4* Wl4 = (float4*)Wl;
        for (int i = tid; i < Hc * Hc / 4; i += 256) Wl4[i] = W4[i];
    }
    const int row0 = blockIdx.x * 32;
    const bool bn = (scale != nullptr);
    for (int i = tid; i < 32 * 32; i += 256) {
        int r = i >> 5, g = i & 31;
        float4 v = ((const float4*)(in + (size_t)(row0 + r) * Hc))[g];
        if (bn) {
            float4 sc = ((const float4*)scale)[g];
            float4 sh = ((const float4*)shift)[g];
            v.x = fmaxf(v.x * sc.x + sh.x, 0.f);
            v.y = fmaxf(v.y * sc.y + sh.y, 0.f);
            v.z = fmaxf(v.z * sc.z + sh.z, 0.f);
            v.w = fmaxf(v.w * sc.w + sh.w, 0.f);
        }
        ((float4*)(inl + r * Hc))[g] = v;
    }
    __syncthreads();

    const int rg = tid >> 5;
    const int cg = tid & 31;
    float acc[4][4] = {{0.f}};
    for (int k = 0; k < Hc; k += 4) {
        float a[4][4], w[4][4];
        #pragma unroll
        for (int r = 0; r < 4; r++) {
            float4 t = *(const float4*)&inl[(rg*4 + r) * Hc + k];
            a[r][0] = t.x; a[r][1] = t.y; a[r][2] = t.z; a[r][3] = t.w;
        }
        #pragma unroll
        for (int kk = 0; kk < 4; kk++) {
            float4 t = *(const float4*)&Wl[(k + kk) * Hc + cg*4];
            w[kk][0] = t.x; w[kk][1] = t.y; w[kk][2] = t.z; w[kk][3] = t.w;
        }
        #pragma unroll
        for (int r = 0; r < 4; r++)
            #pragma unroll
            for (int kk = 0; kk < 4; kk++)
                #pragma unroll
                for (int c = 0; c < 4; c++)
                    acc[r][c] = fmaf(a[r][kk], w[kk][c], acc[r][c]);
    }

    float b4[4];
    #pragma unroll
    for (int c = 0; c < 4; c++) b4[c] = bias[cg*4 + c];
    float s[4] = {0.f,0.f,0.f,0.f}, q[4] = {0.f,0.f,0.f,0.f};
    #pragma unroll
    for (int r = 0; r < 4; r++) {
        float v0 = acc[r][0] + b4[0];
        float v1 = acc[r][1] + b4[1];
        float v2 = acc[r][2] + b4[2];
        float v3 = acc[r][3] + b4[3];
        float4 o; o.x = v0; o.y = v1; o.z = v2; o.w = v3;
        s[0] += v0; s[1] += v1; s[2] += v2; s[3] += v3;
        q[0] += v0*v0; q[1] += v1*v1; q[2] += v2*v2; q[3] += v3*v3;
        *(float4*)&out[(size_t)(row0 + rg*4 + r) * Hc + cg*4] = o;
    }

    __syncthreads();
    #pragma unroll
    for (int c = 0; c < 4; c++) inl[rg * Hc + cg*4 + c] = s[c];
    __syncthreads();
    if (tid < Hc) {
        float t = 0.f;
        #pragma unroll
        for (int g = 0; g < 8; g++) t += inl[g * Hc + tid];
        atomicAdd(&ssum[tid], t);
    }
    __syncthreads();
    #pragma unroll
    for (int c = 0; c < 4; c++) inl[rg * Hc + cg*4 + c] = q[c];
    __syncthreads();
    if (tid < Hc) {
        float t = 0.f;
        #pragma unroll
        for (int g = 0; g < 8; g++) t += inl[g * Hc + tid];
        atomicAdd(&ssq[tid], t);
    }
}

__global__ __launch_bounds__(128) void k_fin(
    const float* __restrict__ sum, const float* __restrict__ sq,
    const float* __restrict__ g, const float* __restrict__ b,
    float* __restrict__ scale, float* __restrict__ shift, float invN)
{
    int t = threadIdx.x;
    float m = sum[t] * invN;
    float v = sq[t] * invN - m * m;
    float s = g[t] * rsqrtf(v + EPSc);
    scale[t] = s;
    shift[t] = b[t] - m * s;
}

__global__ __launch_bounds__(128) void k_final(
    const float* __restrict__ u2, const float* __restrict__ scaleD,
    const float* __restrict__ shiftD, const float* __restrict__ acc0,
    const float* __restrict__ acc1, const float* __restrict__ predW,
    const float* __restrict__ predb, float* __restrict__ out)
{
    __shared__ float h[Hc];
    __shared__ float wl[Hc * Cc];
    __shared__ float lg[Cc], ex[Cc];
    int b = blockIdx.x, t = threadIdx.x;
    for (int i = t; i < Hc * Cc; i += 128) wl[i] = predW[(2*Hc) * Cc + i];
    float x = u2[(size_t)b * Hc + t];
    h[t] = fmaxf(x * scaleD[t] + shiftD[t], 0.f);
    __syncthreads();
    if (t < Cc) {
        float s = predb[t] + acc0[b * Cc + t] + acc1[b * Cc + t];
        for (int d = 0; d < Hc; d++) s += h[d] * wl[d * Cc + t];
        lg[t] = s;
    }
    __syncthreads();
    if (t < Cc) {
        float m = lg[0];
        #pragma unroll
        for (int c = 1; c < Cc; c++) m = fmaxf(m, lg[c]);
        ex[t] = expf(lg[t] - m);
    }
    __syncthreads();
    if (t < Cc) {
        float s = 0.f;
        #pragma unroll
        for (int c = 0; c < Cc; c++) s += ex[c];
        out[b * Cc + t] = ex[t] / s;
    }
}

extern "C" void kernel_launch(void* const* d_in, const int* in_sizes, int n_in,
                              void* d_out, int out_size, void* d_ws, size_t ws_size,
                              hipStream_t stream) {
    const float* h0      = (const float*)d_in[0];
    const int*   parent1 = (const int*)d_in[1];
    const int*   parent2 = (const int*)d_in[2];
    const int*   tree0   = (const int*)d_in[3];
    const int*   tree1   = (const int*)d_in[4];
    const float* m1W1 = (const float*)d_in[5];
    const float* m1b1 = (const float*)d_in[6];
    const float* m1bng = (const float*)d_in[7];
    const float* m1bnb = (const float*)d_in[8];
    const float* m1W2 = (const float*)d_in[9];
    const float* m1b2 = (const float*)d_in[10];
    const float* bn1g = (const float*)d_in[11];
    const float* bn1b = (const float*)d_in[12];
    const float* m2W1 = (const float*)d_in[13];
    const float* m2b1 = (const float*)d_in[14];
    const float* m2bng = (const float*)d_in[15];
    const float* m2bnb = (const float*)d_in[16];
    const float* m2W2 = (const float*)d_in[17];
    const float* m2b2 = (const float*)d_in[18];
    const float* bn2g = (const float*)d_in[19];
    const float* bn2b = (const float*)d_in[20];
    const float* predW = (const float*)d_in[21];
    const float* predb = (const float*)d_in[22];
    float* out = (float*)d_out;

    // ---- workspace layout (floats) ----
    float* ws    = (float*)d_ws;
    float* buf   = ws;                                  // N1*128 (p1 -> t1 -> t4)
    float* p2    = buf + (size_t)N1c * Hc;              // 512*128
    float* u1    = p2 + Bc * Hc;
    float* u2    = u1 + Bc * Hc;
    float* acc0  = u2 + Bc * Hc;                        // 5120
    float* acc1  = acc0 + Bc * Cc;                      // 5120
    float* stats = acc1 + Bc * Cc;                      // 8*128
    float* coeff = stats + 8 * Hc;                      // 8*128
    float* slab  = coeff + 8 * Hc;                      // 512*5120 (10 MB)
    int*   ints  = (int*)(slab + (size_t)512 * Bc * Cc);
    int* cnt1   = ints;                 // 131072
    int* off1   = cnt1 + N1c;           // 131072
    int* cur1   = off1 + N1c;           // 131072
    int* child1 = cur1 + N1c;           // 524288
    int* bsum   = child1 + N0c;         // 512
    int* cnt2   = bsum + 512;           // 512
    int* off2   = cnt2 + Bc;            // 512
    int* cur2   = off2 + Bc;            // 512
    int* child2 = cur2 + Bc;            // 131072

    float* sumA = stats + 0 * Hc; float* sqA = stats + 1 * Hc;
    float* sumB = stats + 2 * Hc; float* sqB = stats + 3 * Hc;
    float* sumC = stats + 4 * Hc; float* sqC = stats + 5 * Hc;
    float* sumD = stats + 6 * Hc; float* sqD = stats + 7 * Hc;
    float* scaleA = coeff + 0 * Hc; float* shiftA = coeff + 1 * Hc;
    float* scaleB = coeff + 2 * Hc; float* shiftB = coeff + 3 * Hc;
    float* scaleC = coeff + 4 * Hc; float* shiftC = coeff + 5 * Hc;
    float* scaleD = coeff + 6 * Hc; float* shiftD = coeff + 7 * Hc;

    // ---- zero what must be zero ----
    hipMemsetAsync(cnt1, 0, 3 * (size_t)N1c * sizeof(int), stream);   // cnt1,off1,cur1
    hipMemsetAsync(cnt2, 0, 3 * (size_t)Bc * sizeof(int), stream);    // cnt2,off2,cur2
    hipMemsetAsync(p2, 0, (size_t)Bc * Hc * sizeof(float), stream);
    hipMemsetAsync(stats, 0, 8 * Hc * sizeof(float), stream);

    // ---- level 1: counting sort over parent1, gather h0 -> p1 (+g0 proj) ----
    k_count<<<N0c / 256, 256, 0, stream>>>(parent1, cnt1, N0c);
    k_scan_local<<<N1c / 256, 256, 0, stream>>>(cnt1, off1, bsum, N1c);
    k_scan_sums<<<1, 512, 0, stream>>>(bsum, N1c / 256);
    k_scan_add<<<N1c / 256, 256, 0, stream>>>(off1, bsum, N1c);
    k_place<<<N0c / 256, 256, 0, stream>>>(parent1, off1, cur1, child1, N0c);
    k_gather<<<512, 512, 0, stream>>>(h0, child1, off1, cnt1, tree0, predW, 0,
                                      nullptr, nullptr, buf, slab, N1c, 1);
    k_reduce<<<20, 256, 0, stream>>>(slab, acc0, 512);

    // ---- layer-1 MLP (in place on buf) ----
    k_gemm<<<N1c / 32, 256, 0, stream>>>(buf, buf, m1W1, m1b1, nullptr, nullptr,
                                         sumA, sqA, N1c);
    k_fin<<<1, 128, 0, stream>>>(sumA, sqA, m1bng, m1bnb, scaleA, shiftA, 1.f / N1c);
    k_gemm<<<N1c / 32, 256, 0, stream>>>(buf, buf, m1W2, m1b2, scaleA, shiftA,
                                         sumB, sqB, N1c);
    k_fin<<<1, 128, 0, stream>>>(sumB, sqB, bn1g, bn1b, scaleB, shiftB, 1.f / N1c);

    // ---- level 2: counting sort over parent2, gather h1 -> p2 (+g1 proj) ----
    k_count<<<N1c / 256, 256, 0, stream>>>(parent2, cnt2, N1c);
    k_scan_local<<<Bc / 256, 256, 0, stream>>>(cnt2, off2, bsum, Bc);
    k_scan_sums<<<1, 512, 0, stream>>>(bsum, Bc / 256);
    k_scan_add<<<Bc / 256, 256, 0, stream>>>(off2, bsum, Bc);
    k_place<<<N1c / 256, 256, 0, stream>>>(parent2, off2, cur2, child2, N1c);
    k_gather<<<256, 512, 0, stream>>>(buf, child2, off2, cnt2, tree1, predW, Hc,
                                      scaleB, shiftB, p2, slab, Bc, 8);
    k_reduce<<<20, 256, 0, stream>>>(slab, acc1, 256);

    // ---- layer-2 MLP (tiny) + final ----
    k_gemm<<<Bc / 32, 256, 0, stream>>>(p2, u1, m2W1, m2b1, nullptr, nullptr,
                                        sumC, sqC, Bc);
    k_fin<<<1, 128, 0, stream>>>(sumC, sqC, m2bng, m2bnb, scaleC, shiftC, 1.f / Bc);
    k_gemm<<<Bc / 32, 256, 0, stream>>>(u1, u2, m2W2, m2b2, scaleC, shiftC,
                                        sumD, sqD, Bc);
    k_fin<<<1, 128, 0, stream>>>(sumD, sqD, bn2g, bn2b, scaleD, shiftD, 1.f / Bc);
    k_final<<<Bc, 128, 0, stream>>>(u2, scaleD, shiftD, acc0, acc1, predW, predb, out);
}

// Round 3
// 813.706 us; speedup vs baseline: 1.7926x; 1.1709x over previous
//
#include <hip/hip_runtime.h>

#define N0c 524288
#define N1c 131072
#define Bc  512
#define Dc  128
#define Hc  128
#define Cc  10
#define EPSc 1e-5f

// ---------------------------------------------------------------------------
// Counting-sort machinery.
// ---------------------------------------------------------------------------
__global__ __launch_bounds__(256) void k_count(const int* __restrict__ idx,
                                               int* __restrict__ cnt, int n)
{
    int r = blockIdx.x * 256 + threadIdx.x;
    if (r < n) atomicAdd(&cnt[idx[r]], 1);
}

// 512-bin histogram with LDS staging (high-contention case).
__global__ __launch_bounds__(256) void k_count512(const int* __restrict__ idx,
                                                  int* __restrict__ cnt, int n)
{
    __shared__ int h[Bc];
    for (int i = threadIdx.x; i < Bc; i += 256) h[i] = 0;
    __syncthreads();
    for (int i = blockIdx.x * 256 + threadIdx.x; i < n; i += gridDim.x * 256)
        atomicAdd(&h[idx[i]], 1);
    __syncthreads();
    for (int i = threadIdx.x; i < Bc; i += 256) {
        int v = h[i];
        if (v) atomicAdd(&cnt[i], v);
    }
}

__global__ __launch_bounds__(256) void k_scan_local(const int* __restrict__ cnt,
                                                    int* __restrict__ off,
                                                    int* __restrict__ bsum, int n)
{
    __shared__ int s[256];
    int t = threadIdx.x;
    int i = blockIdx.x * 256 + t;
    int v = (i < n) ? cnt[i] : 0;
    s[t] = v; __syncthreads();
    for (int o = 1; o < 256; o <<= 1) {
        int x = (t >= o) ? s[t - o] : 0;
        __syncthreads();
        s[t] += x;
        __syncthreads();
    }
    if (i < n) off[i] = s[t] - v;
    if (t == 255) bsum[blockIdx.x] = s[255];
}

__global__ __launch_bounds__(512) void k_scan_sums(int* __restrict__ bsum, int nb)
{
    __shared__ int s[512];
    int t = threadIdx.x;
    int v = (t < nb) ? bsum[t] : 0;
    s[t] = v; __syncthreads();
    for (int o = 1; o < 512; o <<= 1) {
        int x = (t >= o) ? s[t - o] : 0;
        __syncthreads();
        s[t] += x;
        __syncthreads();
    }
    if (t < nb) bsum[t] = s[t] - v;
}

__global__ __launch_bounds__(256) void k_scan_add(int* __restrict__ off,
                                                  const int* __restrict__ bsum, int n)
{
    int i = blockIdx.x * 256 + threadIdx.x;
    if (i < n) off[i] += bsum[blockIdx.x];
}

// single-block exclusive scan of 512 bins
__global__ __launch_bounds__(512) void k_scan512(const int* __restrict__ cnt,
                                                 int* __restrict__ off)
{
    __shared__ int s[512];
    int t = threadIdx.x;
    int v = cnt[t];
    s[t] = v; __syncthreads();
    for (int o = 1; o < 512; o <<= 1) {
        int x = (t >= o) ? s[t - o] : 0;
        __syncthreads();
        s[t] += x;
        __syncthreads();
    }
    off[t] = s[t] - v;
}

__global__ __launch_bounds__(256) void k_place(const int* __restrict__ idx,
                                               const int* __restrict__ off,
                                               int* __restrict__ cur,
                                               int* __restrict__ child, int n)
{
    int r = blockIdx.x * 256 + threadIdx.x;
    if (r < n) {
        int p = idx[r];
        int pos = off[p] + atomicAdd(&cur[p], 1);
        child[pos] = r;
    }
}

// ---------------------------------------------------------------------------
// Lean gather: segment-sum of rows (optional BN+ReLU on load). One 32-lane
// group per (segment, chunk). chunks==1 -> plain store, else atomic add.
// ---------------------------------------------------------------------------
__global__ __launch_bounds__(512) void k_gather_p(
    const float* __restrict__ src, const int* __restrict__ child,
    const int* __restrict__ off, const int* __restrict__ cnt,
    const float* __restrict__ scale, const float* __restrict__ shift,
    float* __restrict__ dst, int nseg, int chunks)
{
    const int lane = threadIdx.x & 31;
    const int sub  = threadIdx.x >> 5;
    const bool bn = (scale != nullptr);
    float4 sc4 = make_float4(1.f,1.f,1.f,1.f), sh4 = make_float4(0.f,0.f,0.f,0.f);
    if (bn) { sc4 = ((const float4*)scale)[lane]; sh4 = ((const float4*)shift)[lane]; }

    const int ntask = nseg * chunks;
    for (int t = blockIdx.x * 16 + sub; t < ntask; t += gridDim.x * 16) {
        const int seg = (chunks == 1) ? t : (t % nseg);
        const int ch  = (chunks == 1) ? 0 : (t / nseg);
        const int beg = off[seg], len = cnt[seg];
        int c0 = (int)(((long long)len * ch) / chunks);
        int c1 = (int)(((long long)len * (ch + 1)) / chunks);
        float4 acc = make_float4(0.f, 0.f, 0.f, 0.f);
        int c = c0;
        for (; c + 4 <= c1; c += 4) {
            int r0 = child[beg+c+0], r1 = child[beg+c+1];
            int r2 = child[beg+c+2], r3 = child[beg+c+3];
            float4 v0 = ((const float4*)(src + (size_t)r0 * Hc))[lane];
            float4 v1 = ((const float4*)(src + (size_t)r1 * Hc))[lane];
            float4 v2 = ((const float4*)(src + (size_t)r2 * Hc))[lane];
            float4 v3 = ((const float4*)(src + (size_t)r3 * Hc))[lane];
            if (bn) {
                v0.x = fmaxf(v0.x*sc4.x+sh4.x,0.f); v0.y = fmaxf(v0.y*sc4.y+sh4.y,0.f);
                v0.z = fmaxf(v0.z*sc4.z+sh4.z,0.f); v0.w = fmaxf(v0.w*sc4.w+sh4.w,0.f);
                v1.x = fmaxf(v1.x*sc4.x+sh4.x,0.f); v1.y = fmaxf(v1.y*sc4.y+sh4.y,0.f);
                v1.z = fmaxf(v1.z*sc4.z+sh4.z,0.f); v1.w = fmaxf(v1.w*sc4.w+sh4.w,0.f);
                v2.x = fmaxf(v2.x*sc4.x+sh4.x,0.f); v2.y = fmaxf(v2.y*sc4.y+sh4.y,0.f);
                v2.z = fmaxf(v2.z*sc4.z+sh4.z,0.f); v2.w = fmaxf(v2.w*sc4.w+sh4.w,0.f);
                v3.x = fmaxf(v3.x*sc4.x+sh4.x,0.f); v3.y = fmaxf(v3.y*sc4.y+sh4.y,0.f);
                v3.z = fmaxf(v3.z*sc4.z+sh4.z,0.f); v3.w = fmaxf(v3.w*sc4.w+sh4.w,0.f);
            }
            acc.x += (v0.x + v1.x) + (v2.x + v3.x);
            acc.y += (v0.y + v1.y) + (v2.y + v3.y);
            acc.z += (v0.z + v1.z) + (v2.z + v3.z);
            acc.w += (v0.w + v1.w) + (v2.w + v3.w);
        }
        for (; c < c1; ++c) {
            int r0 = child[beg + c];
            float4 v0 = ((const float4*)(src + (size_t)r0 * Hc))[lane];
            if (bn) {
                v0.x = fmaxf(v0.x*sc4.x+sh4.x,0.f); v0.y = fmaxf(v0.y*sc4.y+sh4.y,0.f);
                v0.z = fmaxf(v0.z*sc4.z+sh4.z,0.f); v0.w = fmaxf(v0.w*sc4.w+sh4.w,0.f);
            }
            acc.x += v0.x; acc.y += v0.y; acc.z += v0.z; acc.w += v0.w;
        }
        if (chunks == 1) {
            ((float4*)(dst + (size_t)seg * Hc))[lane] = acc;
        } else {
            float* d = dst + (size_t)seg * Hc + lane * 4;
            atomicAdd(d + 0, acc.x);
            atomicAdd(d + 1, acc.y);
            atomicAdd(d + 2, acc.z);
            atomicAdd(d + 3, acc.w);
        }
    }
}

// ---------------------------------------------------------------------------
// Tree-sorted projection: group processes rows of ONE tree, accumulating
// pv[10] in registers; one shfl-reduce per task; 10 global atomics per task.
// ---------------------------------------------------------------------------
__global__ __launch_bounds__(512) void k_proj(
    const float* __restrict__ src, const int* __restrict__ child,
    const int* __restrict__ off, const int* __restrict__ cnt,
    const float* __restrict__ predW, int wrow0,
    const float* __restrict__ scale, const float* __restrict__ shift,
    float* __restrict__ accOut, int chunks)
{
    const int lane = threadIdx.x & 31;
    const int sub  = threadIdx.x >> 5;

    float4 wreg[Cc];
    #pragma unroll
    for (int cc = 0; cc < Cc; cc++) {
        wreg[cc].x = predW[(wrow0 + lane*4 + 0) * Cc + cc];
        wreg[cc].y = predW[(wrow0 + lane*4 + 1) * Cc + cc];
        wreg[cc].z = predW[(wrow0 + lane*4 + 2) * Cc + cc];
        wreg[cc].w = predW[(wrow0 + lane*4 + 3) * Cc + cc];
    }
    const bool bn = (scale != nullptr);
    float4 sc4 = make_float4(1.f,1.f,1.f,1.f), sh4 = make_float4(0.f,0.f,0.f,0.f);
    if (bn) { sc4 = ((const float4*)scale)[lane]; sh4 = ((const float4*)shift)[lane]; }

    const int ntask = Bc * chunks;
    for (int t = blockIdx.x * 16 + sub; t < ntask; t += gridDim.x * 16) {
        const int tr = t & (Bc - 1);
        const int ch = t >> 9;
        const int beg = off[tr], len = cnt[tr];
        int c0 = (int)(((long long)len * ch) / chunks);
        int c1 = (int)(((long long)len * (ch + 1)) / chunks);
        float pv[Cc];
        #pragma unroll
        for (int cc = 0; cc < Cc; cc++) pv[cc] = 0.f;

        int c = c0;
        for (; c + 2 <= c1; c += 2) {
            int r0 = child[beg+c+0], r1 = child[beg+c+1];
            float4 v0 = ((const float4*)(src + (size_t)r0 * Hc))[lane];
            float4 v1 = ((const float4*)(src + (size_t)r1 * Hc))[lane];
            if (bn) {
                v0.x = fmaxf(v0.x*sc4.x+sh4.x,0.f); v0.y = fmaxf(v0.y*sc4.y+sh4.y,0.f);
                v0.z = fmaxf(v0.z*sc4.z+sh4.z,0.f); v0.w = fmaxf(v0.w*sc4.w+sh4.w,0.f);
                v1.x = fmaxf(v1.x*sc4.x+sh4.x,0.f); v1.y = fmaxf(v1.y*sc4.y+sh4.y,0.f);
                v1.z = fmaxf(v1.z*sc4.z+sh4.z,0.f); v1.w = fmaxf(v1.w*sc4.w+sh4.w,0.f);
            }
            #pragma unroll
            for (int cc = 0; cc < Cc; cc++) {
                pv[cc] = fmaf(v0.x, wreg[cc].x, pv[cc]);
                pv[cc] = fmaf(v0.y, wreg[cc].y, pv[cc]);
                pv[cc] = fmaf(v0.z, wreg[cc].z, pv[cc]);
                pv[cc] = fmaf(v0.w, wreg[cc].w, pv[cc]);
                pv[cc] = fmaf(v1.x, wreg[cc].x, pv[cc]);
                pv[cc] = fmaf(v1.y, wreg[cc].y, pv[cc]);
                pv[cc] = fmaf(v1.z, wreg[cc].z, pv[cc]);
                pv[cc] = fmaf(v1.w, wreg[cc].w, pv[cc]);
            }
        }
        if (c < c1) {
            int r0 = child[beg + c];
            float4 v0 = ((const float4*)(src + (size_t)r0 * Hc))[lane];
            if (bn) {
                v0.x = fmaxf(v0.x*sc4.x+sh4.x,0.f); v0.y = fmaxf(v0.y*sc4.y+sh4.y,0.f);
                v0.z = fmaxf(v0.z*sc4.z+sh4.z,0.f); v0.w = fmaxf(v0.w*sc4.w+sh4.w,0.f);
            }
            #pragma unroll
            for (int cc = 0; cc < Cc; cc++) {
                pv[cc] = fmaf(v0.x, wreg[cc].x, pv[cc]);
                pv[cc] = fmaf(v0.y, wreg[cc].y, pv[cc]);
                pv[cc] = fmaf(v0.z, wreg[cc].z, pv[cc]);
                pv[cc] = fmaf(v0.w, wreg[cc].w, pv[cc]);
            }
        }
        #pragma unroll
        for (int o = 16; o; o >>= 1) {
            #pragma unroll
            for (int cc = 0; cc < Cc; cc++) pv[cc] += __shfl_xor(pv[cc], o, 32);
        }
        if (lane == 0) {
            #pragma unroll
            for (int cc = 0; cc < Cc; cc++) atomicAdd(&accOut[tr * Cc + cc], pv[cc]);
        }
    }
}

// ---------------------------------------------------------------------------
// GEMM (unchanged from round 2).
// ---------------------------------------------------------------------------
__global__ __launch_bounds__(256) void k_gemm(
    const float* __restrict__ in, float* __restrict__ out,
    const float* __restrict__ W, const float* __restrict__ bias,
    const float* __restrict__ scale, const float* __restrict__ shift,
    float* __restrict__ ssum, float* __restrict__ ssq, int M)
{
    __shared__ float Wl[Hc * Hc];
    __shared__ float inl[32 * Hc];

    const int tid = threadIdx.x;
    {
        const float4* W4 = (const float4*)W;
        float4* Wl4 = (float4*)Wl;
        for (int i = tid; i < Hc * Hc / 4; i += 256) Wl4[i] = W4[i];
    }
    const int row0 = blockIdx.x * 32;
    const bool bn = (scale != nullptr);
    for (int i = tid; i < 32 * 32; i += 256) {
        int r = i >> 5, g = i & 31;
        float4 v = ((const float4*)(in + (size_t)(row0 + r) * Hc))[g];
        if (bn) {
            float4 sc = ((const float4*)scale)[g];
            float4 sh = ((const float4*)shift)[g];
            v.x = fmaxf(v.x * sc.x + sh.x, 0.f);
            v.y = fmaxf(v.y * sc.y + sh.y, 0.f);
            v.z = fmaxf(v.z * sc.z + sh.z, 0.f);
            v.w = fmaxf(v.w * sc.w + sh.w, 0.f);
        }
        ((float4*)(inl + r * Hc))[g] = v;
    }
    __syncthreads();

    const int rg = tid >> 5;
    const int cg = tid & 31;
    float acc[4][4] = {{0.f}};
    for (int k = 0; k < Hc; k += 4) {
        float a[4][4], w[4][4];
        #pragma unroll
        for (int r = 0; r < 4; r++) {
            float4 t = *(const float4*)&inl[(rg*4 + r) * Hc + k];
            a[r][0] = t.x; a[r][1] = t.y; a[r][2] = t.z; a[r][3] = t.w;
        }
        #pragma unroll
        for (int kk = 0; kk < 4; kk++) {
            float4 t = *(const float4*)&Wl[(k + kk) * Hc + cg*4];
            w[kk][0] = t.x; w[kk][1] = t.y; w[kk][2] = t.z; w[kk][3] = t.w;
        }
        #pragma unroll
        for (int r = 0; r < 4; r++)
            #pragma unroll
            for (int kk = 0; kk < 4; kk++)
                #pragma unroll
                for (int c = 0; c < 4; c++)
                    acc[r][c] = fmaf(a[r][kk], w[kk][c], acc[r][c]);
    }

    float b4[4];
    #pragma unroll
    for (int c = 0; c < 4; c++) b4[c] = bias[cg*4 + c];
    float s[4] = {0.f,0.f,0.f,0.f}, q[4] = {0.f,0.f,0.f,0.f};
    #pragma unroll
    for (int r = 0; r < 4; r++) {
        float v0 = acc[r][0] + b4[0];
        float v1 = acc[r][1] + b4[1];
        float v2 = acc[r][2] + b4[2];
        float v3 = acc[r][3] + b4[3];
        float4 o; o.x = v0; o.y = v1; o.z = v2; o.w = v3;
        s[0] += v0; s[1] += v1; s[2] += v2; s[3] += v3;
        q[0] += v0*v0; q[1] += v1*v1; q[2] += v2*v2; q[3] += v3*v3;
        *(float4*)&out[(size_t)(row0 + rg*4 + r) * Hc + cg*4] = o;
    }

    __syncthreads();
    #pragma unroll
    for (int c = 0; c < 4; c++) inl[rg * Hc + cg*4 + c] = s[c];
    __syncthreads();
    if (tid < Hc) {
        float t = 0.f;
        #pragma unroll
        for (int g = 0; g < 8; g++) t += inl[g * Hc + tid];
        atomicAdd(&ssum[tid], t);
    }
    __syncthreads();
    #pragma unroll
    for (int c = 0; c < 4; c++) inl[rg * Hc + cg*4 + c] = q[c];
    __syncthreads();
    if (tid < Hc) {
        float t = 0.f;
        #pragma unroll
        for (int g = 0; g < 8; g++) t += inl[g * Hc + tid];
        atomicAdd(&ssq[tid], t);
    }
}

__global__ __launch_bounds__(128) void k_fin(
    const float* __restrict__ sum, const float* __restrict__ sq,
    const float* __restrict__ g, const float* __restrict__ b,
    float* __restrict__ scale, float* __restrict__ shift, float invN)
{
    int t = threadIdx.x;
    float m = sum[t] * invN;
    float v = sq[t] * invN - m * m;
    float s = g[t] * rsqrtf(v + EPSc);
    scale[t] = s;
    shift[t] = b[t] - m * s;
}

__global__ __launch_bounds__(128) void k_final(
    const float* __restrict__ u2, const float* __restrict__ scaleD,
    const float* __restrict__ shiftD, const float* __restrict__ acc0,
    const float* __restrict__ acc1, const float* __restrict__ predW,
    const float* __restrict__ predb, float* __restrict__ out)
{
    __shared__ float h[Hc];
    __shared__ float wl[Hc * Cc];
    __shared__ float lg[Cc], ex[Cc];
    int b = blockIdx.x, t = threadIdx.x;
    for (int i = t; i < Hc * Cc; i += 128) wl[i] = predW[(2*Hc) * Cc + i];
    float x = u2[(size_t)b * Hc + t];
    h[t] = fmaxf(x * scaleD[t] + shiftD[t], 0.f);
    __syncthreads();
    if (t < Cc) {
        float s = predb[t] + acc0[b * Cc + t] + acc1[b * Cc + t];
        for (int d = 0; d < Hc; d++) s += h[d] * wl[d * Cc + t];
        lg[t] = s;
    }
    __syncthreads();
    if (t < Cc) {
        float m = lg[0];
        #pragma unroll
        for (int c = 1; c < Cc; c++) m = fmaxf(m, lg[c]);
        ex[t] = expf(lg[t] - m);
    }
    __syncthreads();
    if (t < Cc) {
        float s = 0.f;
        #pragma unroll
        for (int c = 0; c < Cc; c++) s += ex[c];
        out[b * Cc + t] = ex[t] / s;
    }
}

extern "C" void kernel_launch(void* const* d_in, const int* in_sizes, int n_in,
                              void* d_out, int out_size, void* d_ws, size_t ws_size,
                              hipStream_t stream) {
    const float* h0      = (const float*)d_in[0];
    const int*   parent1 = (const int*)d_in[1];
    const int*   parent2 = (const int*)d_in[2];
    const int*   tree0   = (const int*)d_in[3];
    const int*   tree1   = (const int*)d_in[4];
    const float* m1W1 = (const float*)d_in[5];
    const float* m1b1 = (const float*)d_in[6];
    const float* m1bng = (const float*)d_in[7];
    const float* m1bnb = (const float*)d_in[8];
    const float* m1W2 = (const float*)d_in[9];
    const float* m1b2 = (const float*)d_in[10];
    const float* bn1g = (const float*)d_in[11];
    const float* bn1b = (const float*)d_in[12];
    const float* m2W1 = (const float*)d_in[13];
    const float* m2b1 = (const float*)d_in[14];
    const float* m2bng = (const float*)d_in[15];
    const float* m2bnb = (const float*)d_in[16];
    const float* m2W2 = (const float*)d_in[17];
    const float* m2b2 = (const float*)d_in[18];
    const float* bn2g = (const float*)d_in[19];
    const float* bn2b = (const float*)d_in[20];
    const float* predW = (const float*)d_in[21];
    const float* predb = (const float*)d_in[22];
    float* out = (float*)d_out;

    // ---- workspace layout ----
    float* ws    = (float*)d_ws;
    float* buf   = ws;                                  // N1*128
    float* p2    = buf + (size_t)N1c * Hc;              // 512*128
    float* u1    = p2 + Bc * Hc;
    float* u2    = u1 + Bc * Hc;
    float* acc0  = u2 + Bc * Hc;                        // 5120
    float* acc1  = acc0 + Bc * Cc;                      // 5120
    float* stats = acc1 + Bc * Cc;                      // 8*128
    float* coeff = stats + 8 * Hc;                      // 8*128
    int* ints   = (int*)(coeff + 8 * Hc);
    int* cnt1   = ints;                  // 131072
    int* off1   = cnt1 + N1c;            // 131072
    int* cur1   = off1 + N1c;            // 131072
    int* cntT0  = cur1 + N1c;            // 512 (small block start)
    int* offT0  = cntT0 + Bc;
    int* curT0  = offT0 + Bc;
    int* cnt2   = curT0 + Bc;
    int* off2   = cnt2 + Bc;
    int* cur2   = off2 + Bc;
    int* cntT1  = cur2 + Bc;
    int* offT1  = cntT1 + Bc;
    int* curT1  = offT1 + Bc;
    int* bsum   = curT1 + Bc;            // 512 (end of small block: 10*512)
    int* child1 = bsum + Bc;             // 524288
    int* childT0= child1 + N0c;          // 524288
    int* child2 = childT0 + N0c;         // 131072
    int* childT1= child2 + N1c;          // 131072

    float* sumA = stats + 0 * Hc; float* sqA = stats + 1 * Hc;
    float* sumB = stats + 2 * Hc; float* sqB = stats + 3 * Hc;
    float* sumC = stats + 4 * Hc; float* sqC = stats + 5 * Hc;
    float* sumD = stats + 6 * Hc; float* sqD = stats + 7 * Hc;
    float* scaleA = coeff + 0 * Hc; float* shiftA = coeff + 1 * Hc;
    float* scaleB = coeff + 2 * Hc; float* shiftB = coeff + 3 * Hc;
    float* scaleC = coeff + 4 * Hc; float* shiftC = coeff + 5 * Hc;
    float* scaleD = coeff + 6 * Hc; float* shiftD = coeff + 7 * Hc;

    // ---- zero counters / accumulators ----
    hipMemsetAsync(cnt1, 0, 3 * (size_t)N1c * sizeof(int), stream);
    hipMemsetAsync(cntT0, 0, 10 * Bc * sizeof(int), stream);
    hipMemsetAsync(p2, 0, (size_t)Bc * Hc * sizeof(float), stream);
    hipMemsetAsync(acc0, 0, (2 * Bc * Cc + 8 * Hc) * sizeof(float), stream);

    // ---- counting sorts (4x) ----
    k_count<<<N0c / 256, 256, 0, stream>>>(parent1, cnt1, N0c);
    k_count512<<<256, 256, 0, stream>>>(tree0, cntT0, N0c);
    k_count512<<<128, 256, 0, stream>>>(parent2, cnt2, N1c);
    k_count512<<<128, 256, 0, stream>>>(tree1, cntT1, N1c);

    k_scan_local<<<N1c / 256, 256, 0, stream>>>(cnt1, off1, bsum, N1c);
    k_scan_sums<<<1, 512, 0, stream>>>(bsum, N1c / 256);
    k_scan_add<<<N1c / 256, 256, 0, stream>>>(off1, bsum, N1c);
    k_scan512<<<1, 512, 0, stream>>>(cntT0, offT0);
    k_scan512<<<1, 512, 0, stream>>>(cnt2, off2);
    k_scan512<<<1, 512, 0, stream>>>(cntT1, offT1);

    k_place<<<N0c / 256, 256, 0, stream>>>(parent1, off1, cur1, child1, N0c);
    k_place<<<N0c / 256, 256, 0, stream>>>(tree0, offT0, curT0, childT0, N0c);
    k_place<<<N1c / 256, 256, 0, stream>>>(parent2, off2, cur2, child2, N1c);
    k_place<<<N1c / 256, 256, 0, stream>>>(tree1, offT1, curT1, childT1, N1c);

    // ---- level 1: p1 gather + g0 projection ----
    k_gather_p<<<4096, 512, 0, stream>>>(h0, child1, off1, cnt1,
                                         nullptr, nullptr, buf, N1c, 1);
    k_proj<<<1024, 512, 0, stream>>>(h0, childT0, offT0, cntT0, predW, 0,
                                     nullptr, nullptr, acc0, 32);

    // ---- layer-1 MLP (in place) ----
    k_gemm<<<N1c / 32, 256, 0, stream>>>(buf, buf, m1W1, m1b1, nullptr, nullptr,
                                         sumA, sqA, N1c);
    k_fin<<<1, 128, 0, stream>>>(sumA, sqA, m1bng, m1bnb, scaleA, shiftA, 1.f / N1c);
    k_gemm<<<N1c / 32, 256, 0, stream>>>(buf, buf, m1W2, m1b2, scaleA, shiftA,
                                         sumB, sqB, N1c);
    k_fin<<<1, 128, 0, stream>>>(sumB, sqB, bn1g, bn1b, scaleB, shiftB, 1.f / N1c);

    // ---- level 2: p2 gather + g1 projection (BN-B + ReLU on load) ----
    k_gather_p<<<512, 512, 0, stream>>>(buf, child2, off2, cnt2,
                                        scaleB, shiftB, p2, Bc, 16);
    k_proj<<<512, 512, 0, stream>>>(buf, childT1, offT1, cntT1, predW, Hc,
                                    scaleB, shiftB, acc1, 16);

    // ---- layer-2 MLP + final ----
    k_gemm<<<Bc / 32, 256, 0, stream>>>(p2, u1, m2W1, m2b1, nullptr, nullptr,
                                        sumC, sqC, Bc);
    k_fin<<<1, 128, 0, stream>>>(sumC, sqC, m2bng, m2bnb, scaleC, shiftC, 1.f / Bc);
    k_gemm<<<Bc / 32, 256, 0, stream>>>(u1, u2, m2W2, m2b2, scaleC, shiftC,
                                        sumD, sqD, Bc);
    k_fin<<<1, 128, 0, stream>>>(sumD, sqD, bn2g, bn2b, scaleD, shiftD, 1.f / Bc);
    k_final<<<Bc, 128, 0, stream>>>(u2, scaleD, shiftD, acc0, acc1, predW, predb, out);
}

// Round 4
// 591.475 us; speedup vs baseline: 2.4661x; 1.3757x over previous
//
#include <hip/hip_runtime.h>

#define N0c 524288
#define N1c 131072
#define Bc  512
#define Dc  128
#define Hc  128
#define Cc  10
#define EPSc 1e-5f
#define PB_CH 4096

// ---------------------------------------------------------------------------
// Counting-sort machinery.
// ---------------------------------------------------------------------------

// Fused histogram for the two N0-length index arrays: parent1 (128k bins,
// direct low-contention atomics) + tree0 (512 bins, LDS-staged).
__global__ __launch_bounds__(256) void k_count_pair(
    const int* __restrict__ idxA, int* __restrict__ cntA,
    const int* __restrict__ idxB, int* __restrict__ cntB, int n)
{
    __shared__ int h[Bc];
    for (int i = threadIdx.x; i < Bc; i += 256) h[i] = 0;
    __syncthreads();
    for (int i = blockIdx.x * 256 + threadIdx.x; i < n; i += gridDim.x * 256) {
        atomicAdd(&cntA[idxA[i]], 1);
        atomicAdd(&h[idxB[i]], 1);
    }
    __syncthreads();
    for (int i = threadIdx.x; i < Bc; i += 256) {
        int v = h[i];
        if (v) atomicAdd(&cntB[i], v);
    }
}

// 512-bin histogram with LDS staging.
__global__ __launch_bounds__(256) void k_count512(const int* __restrict__ idx,
                                                  int* __restrict__ cnt, int n)
{
    __shared__ int h[Bc];
    for (int i = threadIdx.x; i < Bc; i += 256) h[i] = 0;
    __syncthreads();
    for (int i = blockIdx.x * 256 + threadIdx.x; i < n; i += gridDim.x * 256)
        atomicAdd(&h[idx[i]], 1);
    __syncthreads();
    for (int i = threadIdx.x; i < Bc; i += 256) {
        int v = h[i];
        if (v) atomicAdd(&cnt[i], v);
    }
}

__global__ __launch_bounds__(256) void k_scan_local(const int* __restrict__ cnt,
                                                    int* __restrict__ off,
                                                    int* __restrict__ bsum, int n)
{
    __shared__ int s[256];
    int t = threadIdx.x;
    int i = blockIdx.x * 256 + t;
    int v = (i < n) ? cnt[i] : 0;
    s[t] = v; __syncthreads();
    for (int o = 1; o < 256; o <<= 1) {
        int x = (t >= o) ? s[t - o] : 0;
        __syncthreads();
        s[t] += x;
        __syncthreads();
    }
    if (i < n) off[i] = s[t] - v;
    if (t == 255) bsum[blockIdx.x] = s[255];
}

__global__ __launch_bounds__(512) void k_scan_sums(int* __restrict__ bsum, int nb)
{
    __shared__ int s[512];
    int t = threadIdx.x;
    int v = (t < nb) ? bsum[t] : 0;
    s[t] = v; __syncthreads();
    for (int o = 1; o < 512; o <<= 1) {
        int x = (t >= o) ? s[t - o] : 0;
        __syncthreads();
        s[t] += x;
        __syncthreads();
    }
    if (t < nb) bsum[t] = s[t] - v;
}

__global__ __launch_bounds__(256) void k_scan_add(int* __restrict__ off,
                                                  const int* __restrict__ bsum, int n)
{
    int i = blockIdx.x * 256 + threadIdx.x;
    if (i < n) off[i] += bsum[blockIdx.x];
}

__global__ __launch_bounds__(512) void k_scan512(const int* __restrict__ cnt,
                                                 int* __restrict__ off)
{
    __shared__ int s[512];
    int t = threadIdx.x;
    int v = cnt[t];
    s[t] = v; __syncthreads();
    for (int o = 1; o < 512; o <<= 1) {
        int x = (t >= o) ? s[t - o] : 0;
        __syncthreads();
        s[t] += x;
        __syncthreads();
    }
    off[t] = s[t] - v;
}

// Low-contention place (wide bins, e.g. parent1 with ~4 children/bin).
__global__ __launch_bounds__(256) void k_place(const int* __restrict__ idx,
                                               const int* __restrict__ off,
                                               int* __restrict__ cur,
                                               int* __restrict__ child, int n)
{
    int r = blockIdx.x * 256 + threadIdx.x;
    if (r < n) {
        int p = idx[r];
        int pos = off[p] + atomicAdd(&cur[p], 1);
        child[pos] = r;
    }
}

// Block-binned place for 512-bin sorts: per-block LDS histogram, one global
// reservation atomic per (block,bin), LDS-cursor scatter. Kills the ~1000-way
// global atomic contention that made k_place latency-bound (160us -> ~20us).
__global__ __launch_bounds__(1024) void k_place_bin(
    const int* __restrict__ idx, const int* __restrict__ off,
    int* __restrict__ cur, int* __restrict__ child, int n)
{
    __shared__ int h[Bc];
    __shared__ int base[Bc];
    const int tid = threadIdx.x;
    for (int c0 = blockIdx.x * PB_CH; c0 < n; c0 += gridDim.x * PB_CH) {
        const int c1 = min(c0 + PB_CH, n);
        for (int i = tid; i < Bc; i += 1024) h[i] = 0;
        __syncthreads();
        for (int i = c0 + tid; i < c1; i += 1024)
            atomicAdd(&h[idx[i]], 1);
        __syncthreads();
        for (int i = tid; i < Bc; i += 1024) {
            int v = h[i];
            base[i] = v ? atomicAdd(&cur[i], v) : 0;
        }
        __syncthreads();
        for (int i = tid; i < Bc; i += 1024) h[i] = 0;
        __syncthreads();
        for (int i = c0 + tid; i < c1; i += 1024) {
            int b = idx[i];
            int p = atomicAdd(&h[b], 1);
            child[off[b] + base[b] + p] = i;
        }
        __syncthreads();
    }
}

// ---------------------------------------------------------------------------
// Lean gather: segment-sum of rows (optional BN+ReLU on load).
// ---------------------------------------------------------------------------
__global__ __launch_bounds__(512) void k_gather_p(
    const float* __restrict__ src, const int* __restrict__ child,
    const int* __restrict__ off, const int* __restrict__ cnt,
    const float* __restrict__ scale, const float* __restrict__ shift,
    float* __restrict__ dst, int nseg, int chunks)
{
    const int lane = threadIdx.x & 31;
    const int sub  = threadIdx.x >> 5;
    const bool bn = (scale != nullptr);
    float4 sc4 = make_float4(1.f,1.f,1.f,1.f), sh4 = make_float4(0.f,0.f,0.f,0.f);
    if (bn) { sc4 = ((const float4*)scale)[lane]; sh4 = ((const float4*)shift)[lane]; }

    const int ntask = nseg * chunks;
    for (int t = blockIdx.x * 16 + sub; t < ntask; t += gridDim.x * 16) {
        const int seg = (chunks == 1) ? t : (t % nseg);
        const int ch  = (chunks == 1) ? 0 : (t / nseg);
        const int beg = off[seg], len = cnt[seg];
        int c0 = (int)(((long long)len * ch) / chunks);
        int c1 = (int)(((long long)len * (ch + 1)) / chunks);
        float4 acc = make_float4(0.f, 0.f, 0.f, 0.f);
        int c = c0;
        for (; c + 4 <= c1; c += 4) {
            int r0 = child[beg+c+0], r1 = child[beg+c+1];
            int r2 = child[beg+c+2], r3 = child[beg+c+3];
            float4 v0 = ((const float4*)(src + (size_t)r0 * Hc))[lane];
            float4 v1 = ((const float4*)(src + (size_t)r1 * Hc))[lane];
            float4 v2 = ((const float4*)(src + (size_t)r2 * Hc))[lane];
            float4 v3 = ((const float4*)(src + (size_t)r3 * Hc))[lane];
            if (bn) {
                v0.x = fmaxf(v0.x*sc4.x+sh4.x,0.f); v0.y = fmaxf(v0.y*sc4.y+sh4.y,0.f);
                v0.z = fmaxf(v0.z*sc4.z+sh4.z,0.f); v0.w = fmaxf(v0.w*sc4.w+sh4.w,0.f);
                v1.x = fmaxf(v1.x*sc4.x+sh4.x,0.f); v1.y = fmaxf(v1.y*sc4.y+sh4.y,0.f);
                v1.z = fmaxf(v1.z*sc4.z+sh4.z,0.f); v1.w = fmaxf(v1.w*sc4.w+sh4.w,0.f);
                v2.x = fmaxf(v2.x*sc4.x+sh4.x,0.f); v2.y = fmaxf(v2.y*sc4.y+sh4.y,0.f);
                v2.z = fmaxf(v2.z*sc4.z+sh4.z,0.f); v2.w = fmaxf(v2.w*sc4.w+sh4.w,0.f);
                v3.x = fmaxf(v3.x*sc4.x+sh4.x,0.f); v3.y = fmaxf(v3.y*sc4.y+sh4.y,0.f);
                v3.z = fmaxf(v3.z*sc4.z+sh4.z,0.f); v3.w = fmaxf(v3.w*sc4.w+sh4.w,0.f);
            }
            acc.x += (v0.x + v1.x) + (v2.x + v3.x);
            acc.y += (v0.y + v1.y) + (v2.y + v3.y);
            acc.z += (v0.z + v1.z) + (v2.z + v3.z);
            acc.w += (v0.w + v1.w) + (v2.w + v3.w);
        }
        for (; c < c1; ++c) {
            int r0 = child[beg + c];
            float4 v0 = ((const float4*)(src + (size_t)r0 * Hc))[lane];
            if (bn) {
                v0.x = fmaxf(v0.x*sc4.x+sh4.x,0.f); v0.y = fmaxf(v0.y*sc4.y+sh4.y,0.f);
                v0.z = fmaxf(v0.z*sc4.z+sh4.z,0.f); v0.w = fmaxf(v0.w*sc4.w+sh4.w,0.f);
            }
            acc.x += v0.x; acc.y += v0.y; acc.z += v0.z; acc.w += v0.w;
        }
        if (chunks == 1) {
            ((float4*)(dst + (size_t)seg * Hc))[lane] = acc;
        } else {
            float* d = dst + (size_t)seg * Hc + lane * 4;
            atomicAdd(d + 0, acc.x);
            atomicAdd(d + 1, acc.y);
            atomicAdd(d + 2, acc.z);
            atomicAdd(d + 3, acc.w);
        }
    }
}

// ---------------------------------------------------------------------------
// Tree-sorted projection: register pv[10] across a task's rows, one shfl
// reduce + 10 global atomics per task.
// ---------------------------------------------------------------------------
__global__ __launch_bounds__(512) void k_proj(
    const float* __restrict__ src, const int* __restrict__ child,
    const int* __restrict__ off, const int* __restrict__ cnt,
    const float* __restrict__ predW, int wrow0,
    const float* __restrict__ scale, const float* __restrict__ shift,
    float* __restrict__ accOut, int chunks)
{
    const int lane = threadIdx.x & 31;
    const int sub  = threadIdx.x >> 5;

    float4 wreg[Cc];
    #pragma unroll
    for (int cc = 0; cc < Cc; cc++) {
        wreg[cc].x = predW[(wrow0 + lane*4 + 0) * Cc + cc];
        wreg[cc].y = predW[(wrow0 + lane*4 + 1) * Cc + cc];
        wreg[cc].z = predW[(wrow0 + lane*4 + 2) * Cc + cc];
        wreg[cc].w = predW[(wrow0 + lane*4 + 3) * Cc + cc];
    }
    const bool bn = (scale != nullptr);
    float4 sc4 = make_float4(1.f,1.f,1.f,1.f), sh4 = make_float4(0.f,0.f,0.f,0.f);
    if (bn) { sc4 = ((const float4*)scale)[lane]; sh4 = ((const float4*)shift)[lane]; }

    const int ntask = Bc * chunks;
    for (int t = blockIdx.x * 16 + sub; t < ntask; t += gridDim.x * 16) {
        const int tr = t & (Bc - 1);
        const int ch = t >> 9;
        const int beg = off[tr], len = cnt[tr];
        int c0 = (int)(((long long)len * ch) / chunks);
        int c1 = (int)(((long long)len * (ch + 1)) / chunks);
        float pv[Cc];
        #pragma unroll
        for (int cc = 0; cc < Cc; cc++) pv[cc] = 0.f;

        int c = c0;
        for (; c + 2 <= c1; c += 2) {
            int r0 = child[beg+c+0], r1 = child[beg+c+1];
            float4 v0 = ((const float4*)(src + (size_t)r0 * Hc))[lane];
            float4 v1 = ((const float4*)(src + (size_t)r1 * Hc))[lane];
            if (bn) {
                v0.x = fmaxf(v0.x*sc4.x+sh4.x,0.f); v0.y = fmaxf(v0.y*sc4.y+sh4.y,0.f);
                v0.z = fmaxf(v0.z*sc4.z+sh4.z,0.f); v0.w = fmaxf(v0.w*sc4.w+sh4.w,0.f);
                v1.x = fmaxf(v1.x*sc4.x+sh4.x,0.f); v1.y = fmaxf(v1.y*sc4.y+sh4.y,0.f);
                v1.z = fmaxf(v1.z*sc4.z+sh4.z,0.f); v1.w = fmaxf(v1.w*sc4.w+sh4.w,0.f);
            }
            #pragma unroll
            for (int cc = 0; cc < Cc; cc++) {
                pv[cc] = fmaf(v0.x, wreg[cc].x, pv[cc]);
                pv[cc] = fmaf(v0.y, wreg[cc].y, pv[cc]);
                pv[cc] = fmaf(v0.z, wreg[cc].z, pv[cc]);
                pv[cc] = fmaf(v0.w, wreg[cc].w, pv[cc]);
                pv[cc] = fmaf(v1.x, wreg[cc].x, pv[cc]);
                pv[cc] = fmaf(v1.y, wreg[cc].y, pv[cc]);
                pv[cc] = fmaf(v1.z, wreg[cc].z, pv[cc]);
                pv[cc] = fmaf(v1.w, wreg[cc].w, pv[cc]);
            }
        }
        if (c < c1) {
            int r0 = child[beg + c];
            float4 v0 = ((const float4*)(src + (size_t)r0 * Hc))[lane];
            if (bn) {
                v0.x = fmaxf(v0.x*sc4.x+sh4.x,0.f); v0.y = fmaxf(v0.y*sc4.y+sh4.y,0.f);
                v0.z = fmaxf(v0.z*sc4.z+sh4.z,0.f); v0.w = fmaxf(v0.w*sc4.w+sh4.w,0.f);
            }
            #pragma unroll
            for (int cc = 0; cc < Cc; cc++) {
                pv[cc] = fmaf(v0.x, wreg[cc].x, pv[cc]);
                pv[cc] = fmaf(v0.y, wreg[cc].y, pv[cc]);
                pv[cc] = fmaf(v0.z, wreg[cc].z, pv[cc]);
                pv[cc] = fmaf(v0.w, wreg[cc].w, pv[cc]);
            }
        }
        #pragma unroll
        for (int o = 16; o; o >>= 1) {
            #pragma unroll
            for (int cc = 0; cc < Cc; cc++) pv[cc] += __shfl_xor(pv[cc], o, 32);
        }
        if (lane == 0) {
            #pragma unroll
            for (int cc = 0; cc < Cc; cc++) atomicAdd(&accOut[tr * Cc + cc], pv[cc]);
        }
    }
}

// ---------------------------------------------------------------------------
// GEMM.
// ---------------------------------------------------------------------------
__global__ __launch_bounds__(256) void k_gemm(
    const float* __restrict__ in, float* __restrict__ out,
    const float* __restrict__ W, const float* __restrict__ bias,
    const float* __restrict__ scale, const float* __restrict__ shift,
    float* __restrict__ ssum, float* __restrict__ ssq, int M)
{
    __shared__ float Wl[Hc * Hc];
    __shared__ float inl[32 * Hc];

    const int tid = threadIdx.x;
    {
        const float4* W4 = (const float4*)W;
        float4* Wl4 = (float4*)Wl;
        for (int i = tid; i < Hc * Hc / 4; i += 256) Wl4[i] = W4[i];
    }
    const int row0 = blockIdx.x * 32;
    const bool bn = (scale != nullptr);
    for (int i = tid; i < 32 * 32; i += 256) {
        int r = i >> 5, g = i & 31;
        float4 v = ((const float4*)(in + (size_t)(row0 + r) * Hc))[g];
        if (bn) {
            float4 sc = ((const float4*)scale)[g];
            float4 sh = ((const float4*)shift)[g];
            v.x = fmaxf(v.x * sc.x + sh.x, 0.f);
            v.y = fmaxf(v.y * sc.y + sh.y, 0.f);
            v.z = fmaxf(v.z * sc.z + sh.z, 0.f);
            v.w = fmaxf(v.w * sc.w + sh.w, 0.f);
        }
        ((float4*)(inl + r * Hc))[g] = v;
    }
    __syncthreads();

    const int rg = tid >> 5;
    const int cg = tid & 31;
    float acc[4][4] = {{0.f}};
    for (int k = 0; k < Hc; k += 4) {
        float a[4][4], w[4][4];
        #pragma unroll
        for (int r = 0; r < 4; r++) {
            float4 t = *(const float4*)&inl[(rg*4 + r) * Hc + k];
            a[r][0] = t.x; a[r][1] = t.y; a[r][2] = t.z; a[r][3] = t.w;
        }
        #pragma unroll
        for (int kk = 0; kk < 4; kk++) {
            float4 t = *(const float4*)&Wl[(k + kk) * Hc + cg*4];
            w[kk][0] = t.x; w[kk][1] = t.y; w[kk][2] = t.z; w[kk][3] = t.w;
        }
        #pragma unroll
        for (int r = 0; r < 4; r++)
            #pragma unroll
            for (int kk = 0; kk < 4; kk++)
                #pragma unroll
                for (int c = 0; c < 4; c++)
                    acc[r][c] = fmaf(a[r][kk], w[kk][c], acc[r][c]);
    }

    float b4[4];
    #pragma unroll
    for (int c = 0; c < 4; c++) b4[c] = bias[cg*4 + c];
    float s[4] = {0.f,0.f,0.f,0.f}, q[4] = {0.f,0.f,0.f,0.f};
    #pragma unroll
    for (int r = 0; r < 4; r++) {
        float v0 = acc[r][0] + b4[0];
        float v1 = acc[r][1] + b4[1];
        float v2 = acc[r][2] + b4[2];
        float v3 = acc[r][3] + b4[3];
        float4 o; o.x = v0; o.y = v1; o.z = v2; o.w = v3;
        s[0] += v0; s[1] += v1; s[2] += v2; s[3] += v3;
        q[0] += v0*v0; q[1] += v1*v1; q[2] += v2*v2; q[3] += v3*v3;
        *(float4*)&out[(size_t)(row0 + rg*4 + r) * Hc + cg*4] = o;
    }

    __syncthreads();
    #pragma unroll
    for (int c = 0; c < 4; c++) inl[rg * Hc + cg*4 + c] = s[c];
    __syncthreads();
    if (tid < Hc) {
        float t = 0.f;
        #pragma unroll
        for (int g = 0; g < 8; g++) t += inl[g * Hc + tid];
        atomicAdd(&ssum[tid], t);
    }
    __syncthreads();
    #pragma unroll
    for (int c = 0; c < 4; c++) inl[rg * Hc + cg*4 + c] = q[c];
    __syncthreads();
    if (tid < Hc) {
        float t = 0.f;
        #pragma unroll
        for (int g = 0; g < 8; g++) t += inl[g * Hc + tid];
        atomicAdd(&ssq[tid], t);
    }
}

__global__ __launch_bounds__(128) void k_fin(
    const float* __restrict__ sum, const float* __restrict__ sq,
    const float* __restrict__ g, const float* __restrict__ b,
    float* __restrict__ scale, float* __restrict__ shift, float invN)
{
    int t = threadIdx.x;
    float m = sum[t] * invN;
    float v = sq[t] * invN - m * m;
    float s = g[t] * rsqrtf(v + EPSc);
    scale[t] = s;
    shift[t] = b[t] - m * s;
}

__global__ __launch_bounds__(128) void k_final(
    const float* __restrict__ u2, const float* __restrict__ scaleD,
    const float* __restrict__ shiftD, const float* __restrict__ acc0,
    const float* __restrict__ acc1, const float* __restrict__ predW,
    const float* __restrict__ predb, float* __restrict__ out)
{
    __shared__ float h[Hc];
    __shared__ float wl[Hc * Cc];
    __shared__ float lg[Cc], ex[Cc];
    int b = blockIdx.x, t = threadIdx.x;
    for (int i = t; i < Hc * Cc; i += 128) wl[i] = predW[(2*Hc) * Cc + i];
    float x = u2[(size_t)b * Hc + t];
    h[t] = fmaxf(x * scaleD[t] + shiftD[t], 0.f);
    __syncthreads();
    if (t < Cc) {
        float s = predb[t] + acc0[b * Cc + t] + acc1[b * Cc + t];
        for (int d = 0; d < Hc; d++) s += h[d] * wl[d * Cc + t];
        lg[t] = s;
    }
    __syncthreads();
    if (t < Cc) {
        float m = lg[0];
        #pragma unroll
        for (int c = 1; c < Cc; c++) m = fmaxf(m, lg[c]);
        ex[t] = expf(lg[t] - m);
    }
    __syncthreads();
    if (t < Cc) {
        float s = 0.f;
        #pragma unroll
        for (int c = 0; c < Cc; c++) s += ex[c];
        out[b * Cc + t] = ex[t] / s;
    }
}

extern "C" void kernel_launch(void* const* d_in, const int* in_sizes, int n_in,
                              void* d_out, int out_size, void* d_ws, size_t ws_size,
                              hipStream_t stream) {
    const float* h0      = (const float*)d_in[0];
    const int*   parent1 = (const int*)d_in[1];
    const int*   parent2 = (const int*)d_in[2];
    const int*   tree0   = (const int*)d_in[3];
    const int*   tree1   = (const int*)d_in[4];
    const float* m1W1 = (const float*)d_in[5];
    const float* m1b1 = (const float*)d_in[6];
    const float* m1bng = (const float*)d_in[7];
    const float* m1bnb = (const float*)d_in[8];
    const float* m1W2 = (const float*)d_in[9];
    const float* m1b2 = (const float*)d_in[10];
    const float* bn1g = (const float*)d_in[11];
    const float* bn1b = (const float*)d_in[12];
    const float* m2W1 = (const float*)d_in[13];
    const float* m2b1 = (const float*)d_in[14];
    const float* m2bng = (const float*)d_in[15];
    const float* m2bnb = (const float*)d_in[16];
    const float* m2W2 = (const float*)d_in[17];
    const float* m2b2 = (const float*)d_in[18];
    const float* bn2g = (const float*)d_in[19];
    const float* bn2b = (const float*)d_in[20];
    const float* predW = (const float*)d_in[21];
    const float* predb = (const float*)d_in[22];
    float* out = (float*)d_out;

    // ---- workspace layout ----
    float* ws    = (float*)d_ws;
    float* buf   = ws;                                  // N1*128
    float* p2    = buf + (size_t)N1c * Hc;              // 512*128
    float* u1    = p2 + Bc * Hc;
    float* u2    = u1 + Bc * Hc;
    float* acc0  = u2 + Bc * Hc;                        // 5120
    float* acc1  = acc0 + Bc * Cc;                      // 5120
    float* stats = acc1 + Bc * Cc;                      // 8*128
    float* coeff = stats + 8 * Hc;                      // 8*128
    int* ints   = (int*)(coeff + 8 * Hc);
    int* cnt1   = ints;                  // 131072
    int* off1   = cnt1 + N1c;            // 131072
    int* cur1   = off1 + N1c;            // 131072
    int* cntT0  = cur1 + N1c;            // 512 (small block start)
    int* offT0  = cntT0 + Bc;
    int* curT0  = offT0 + Bc;
    int* cnt2   = curT0 + Bc;
    int* off2   = cnt2 + Bc;
    int* cur2   = off2 + Bc;
    int* cntT1  = cur2 + Bc;
    int* offT1  = cntT1 + Bc;
    int* curT1  = offT1 + Bc;
    int* bsum   = curT1 + Bc;            // 512 (end of small block: 10*512)
    int* child1 = bsum + Bc;             // 524288
    int* childT0= child1 + N0c;          // 524288
    int* child2 = childT0 + N0c;         // 131072
    int* childT1= child2 + N1c;          // 131072

    float* sumA = stats + 0 * Hc; float* sqA = stats + 1 * Hc;
    float* sumB = stats + 2 * Hc; float* sqB = stats + 3 * Hc;
    float* sumC = stats + 4 * Hc; float* sqC = stats + 5 * Hc;
    float* sumD = stats + 6 * Hc; float* sqD = stats + 7 * Hc;
    float* scaleA = coeff + 0 * Hc; float* shiftA = coeff + 1 * Hc;
    float* scaleB = coeff + 2 * Hc; float* shiftB = coeff + 3 * Hc;
    float* scaleC = coeff + 4 * Hc; float* shiftC = coeff + 5 * Hc;
    float* scaleD = coeff + 6 * Hc; float* shiftD = coeff + 7 * Hc;

    // ---- zero counters / accumulators ----
    hipMemsetAsync(cnt1, 0, 3 * (size_t)N1c * sizeof(int), stream);
    hipMemsetAsync(cntT0, 0, 10 * Bc * sizeof(int), stream);
    hipMemsetAsync(p2, 0, (size_t)Bc * Hc * sizeof(float), stream);
    hipMemsetAsync(acc0, 0, (2 * Bc * Cc + 8 * Hc) * sizeof(float), stream);

    // ---- counting sorts ----
    k_count_pair<<<512, 256, 0, stream>>>(parent1, cnt1, tree0, cntT0, N0c);
    k_count512<<<128, 256, 0, stream>>>(parent2, cnt2, N1c);
    k_count512<<<128, 256, 0, stream>>>(tree1, cntT1, N1c);

    k_scan_local<<<N1c / 256, 256, 0, stream>>>(cnt1, off1, bsum, N1c);
    k_scan_sums<<<1, 512, 0, stream>>>(bsum, N1c / 256);
    k_scan_add<<<N1c / 256, 256, 0, stream>>>(off1, bsum, N1c);
    k_scan512<<<1, 512, 0, stream>>>(cntT0, offT0);
    k_scan512<<<1, 512, 0, stream>>>(cnt2, off2);
    k_scan512<<<1, 512, 0, stream>>>(cntT1, offT1);

    k_place<<<N0c / 256, 256, 0, stream>>>(parent1, off1, cur1, child1, N0c);
    k_place_bin<<<(N0c + PB_CH - 1) / PB_CH, 1024, 0, stream>>>(tree0, offT0, curT0, childT0, N0c);
    k_place_bin<<<(N1c + PB_CH - 1) / PB_CH, 1024, 0, stream>>>(parent2, off2, cur2, child2, N1c);
    k_place_bin<<<(N1c + PB_CH - 1) / PB_CH, 1024, 0, stream>>>(tree1, offT1, curT1, childT1, N1c);

    // ---- level 1: p1 gather + g0 projection ----
    k_gather_p<<<4096, 512, 0, stream>>>(h0, child1, off1, cnt1,
                                         nullptr, nullptr, buf, N1c, 1);
    k_proj<<<1024, 512, 0, stream>>>(h0, childT0, offT0, cntT0, predW, 0,
                                     nullptr, nullptr, acc0, 32);

    // ---- layer-1 MLP (in place) ----
    k_gemm<<<N1c / 32, 256, 0, stream>>>(buf, buf, m1W1, m1b1, nullptr, nullptr,
                                         sumA, sqA, N1c);
    k_fin<<<1, 128, 0, stream>>>(sumA, sqA, m1bng, m1bnb, scaleA, shiftA, 1.f / N1c);
    k_gemm<<<N1c / 32, 256, 0, stream>>>(buf, buf, m1W2, m1b2, scaleA, shiftA,
                                         sumB, sqB, N1c);
    k_fin<<<1, 128, 0, stream>>>(sumB, sqB, bn1g, bn1b, scaleB, shiftB, 1.f / N1c);

    // ---- level 2: p2 gather + g1 projection (BN-B + ReLU on load) ----
    k_gather_p<<<512, 512, 0, stream>>>(buf, child2, off2, cnt2,
                                        scaleB, shiftB, p2, Bc, 16);
    k_proj<<<512, 512, 0, stream>>>(buf, childT1, offT1, cntT1, predW, Hc,
                                    scaleB, shiftB, acc1, 16);

    // ---- layer-2 MLP + final ----
    k_gemm<<<Bc / 32, 256, 0, stream>>>(p2, u1, m2W1, m2b1, nullptr, nullptr,
                                        sumC, sqC, Bc);
    k_fin<<<1, 128, 0, stream>>>(sumC, sqC, m2bng, m2bnb, scaleC, shiftC, 1.f / Bc);
    k_gemm<<<Bc / 32, 256, 0, stream>>>(u1, u2, m2W2, m2b2, scaleC, shiftC,
                                        sumD, sqD, Bc);
    k_fin<<<1, 128, 0, stream>>>(sumD, sqD, bn2g, bn2b, scaleD, shiftD, 1.f / Bc);
    k_final<<<Bc, 128, 0, stream>>>(u2, scaleD, shiftD, acc0, acc1, predW, predb, out);
}

// Round 5
// 494.681 us; speedup vs baseline: 2.9486x; 1.1957x over previous
//
#include <hip/hip_runtime.h>

#define N0c 524288
#define N1c 131072
#define Bc  512
#define Dc  128
#define Hc  128
#define Cc  10
#define EPSc 1e-5f
#define PB_CH 4096

typedef unsigned short u16;
typedef __attribute__((ext_vector_type(8))) short bf16x8;
typedef __attribute__((ext_vector_type(4))) float f32x4;

__device__ __forceinline__ u16 f2bf(float f) {
    unsigned u = __builtin_bit_cast(unsigned, f);
    unsigned r = (u + 0x7fffu + ((u >> 16) & 1u)) >> 16;
    return (u16)r;
}
__device__ __forceinline__ float bf2f(u16 h) {
    return __builtin_bit_cast(float, (unsigned)h << 16);
}

// ---------------------------------------------------------------------------
// Counting-sort machinery (unchanged from round 4).
// ---------------------------------------------------------------------------
__global__ __launch_bounds__(256) void k_count_pair(
    const int* __restrict__ idxA, int* __restrict__ cntA,
    const int* __restrict__ idxB, int* __restrict__ cntB, int n)
{
    __shared__ int h[Bc];
    for (int i = threadIdx.x; i < Bc; i += 256) h[i] = 0;
    __syncthreads();
    for (int i = blockIdx.x * 256 + threadIdx.x; i < n; i += gridDim.x * 256) {
        atomicAdd(&cntA[idxA[i]], 1);
        atomicAdd(&h[idxB[i]], 1);
    }
    __syncthreads();
    for (int i = threadIdx.x; i < Bc; i += 256) {
        int v = h[i];
        if (v) atomicAdd(&cntB[i], v);
    }
}

__global__ __launch_bounds__(256) void k_count512(const int* __restrict__ idx,
                                                  int* __restrict__ cnt, int n)
{
    __shared__ int h[Bc];
    for (int i = threadIdx.x; i < Bc; i += 256) h[i] = 0;
    __syncthreads();
    for (int i = blockIdx.x * 256 + threadIdx.x; i < n; i += gridDim.x * 256)
        atomicAdd(&h[idx[i]], 1);
    __syncthreads();
    for (int i = threadIdx.x; i < Bc; i += 256) {
        int v = h[i];
        if (v) atomicAdd(&cnt[i], v);
    }
}

__global__ __launch_bounds__(256) void k_scan_local(const int* __restrict__ cnt,
                                                    int* __restrict__ off,
                                                    int* __restrict__ bsum, int n)
{
    __shared__ int s[256];
    int t = threadIdx.x;
    int i = blockIdx.x * 256 + t;
    int v = (i < n) ? cnt[i] : 0;
    s[t] = v; __syncthreads();
    for (int o = 1; o < 256; o <<= 1) {
        int x = (t >= o) ? s[t - o] : 0;
        __syncthreads();
        s[t] += x;
        __syncthreads();
    }
    if (i < n) off[i] = s[t] - v;
    if (t == 255) bsum[blockIdx.x] = s[255];
}

__global__ __launch_bounds__(512) void k_scan_sums(int* __restrict__ bsum, int nb)
{
    __shared__ int s[512];
    int t = threadIdx.x;
    int v = (t < nb) ? bsum[t] : 0;
    s[t] = v; __syncthreads();
    for (int o = 1; o < 512; o <<= 1) {
        int x = (t >= o) ? s[t - o] : 0;
        __syncthreads();
        s[t] += x;
        __syncthreads();
    }
    if (t < nb) bsum[t] = s[t] - v;
}

__global__ __launch_bounds__(256) void k_scan_add(int* __restrict__ off,
                                                  const int* __restrict__ bsum, int n)
{
    int i = blockIdx.x * 256 + threadIdx.x;
    if (i < n) off[i] += bsum[blockIdx.x];
}

__global__ __launch_bounds__(512) void k_scan512(const int* __restrict__ cnt,
                                                 int* __restrict__ off)
{
    __shared__ int s[512];
    int t = threadIdx.x;
    int v = cnt[t];
    s[t] = v; __syncthreads();
    for (int o = 1; o < 512; o <<= 1) {
        int x = (t >= o) ? s[t - o] : 0;
        __syncthreads();
        s[t] += x;
        __syncthreads();
    }
    off[t] = s[t] - v;
}

__global__ __launch_bounds__(256) void k_place(const int* __restrict__ idx,
                                               const int* __restrict__ off,
                                               int* __restrict__ cur,
                                               int* __restrict__ child, int n)
{
    int r = blockIdx.x * 256 + threadIdx.x;
    if (r < n) {
        int p = idx[r];
        int pos = off[p] + atomicAdd(&cur[p], 1);
        child[pos] = r;
    }
}

__global__ __launch_bounds__(1024) void k_place_bin(
    const int* __restrict__ idx, const int* __restrict__ off,
    int* __restrict__ cur, int* __restrict__ child, int n)
{
    __shared__ int h[Bc];
    __shared__ int base[Bc];
    const int tid = threadIdx.x;
    for (int c0 = blockIdx.x * PB_CH; c0 < n; c0 += gridDim.x * PB_CH) {
        const int c1 = min(c0 + PB_CH, n);
        for (int i = tid; i < Bc; i += 1024) h[i] = 0;
        __syncthreads();
        for (int i = c0 + tid; i < c1; i += 1024)
            atomicAdd(&h[idx[i]], 1);
        __syncthreads();
        for (int i = tid; i < Bc; i += 1024) {
            int v = h[i];
            base[i] = v ? atomicAdd(&cur[i], v) : 0;
        }
        __syncthreads();
        for (int i = tid; i < Bc; i += 1024) h[i] = 0;
        __syncthreads();
        for (int i = c0 + tid; i < c1; i += 1024) {
            int b = idx[i];
            int p = atomicAdd(&h[b], 1);
            child[off[b] + base[b] + p] = i;
        }
        __syncthreads();
    }
}

// ---------------------------------------------------------------------------
// Level-1 gather: h0 (fp32) -> p1 stored as split bf16 (hi+lo). One 32-lane
// group per segment, plain stores.
// ---------------------------------------------------------------------------
__global__ __launch_bounds__(512) void k_gather_split(
    const float* __restrict__ src, const int* __restrict__ child,
    const int* __restrict__ off, const int* __restrict__ cnt,
    u16* __restrict__ dhi, u16* __restrict__ dlo, int nseg)
{
    const int lane = threadIdx.x & 31;
    const int sub  = threadIdx.x >> 5;
    for (int seg = blockIdx.x * 16 + sub; seg < nseg; seg += gridDim.x * 16) {
        const int beg = off[seg], len = cnt[seg];
        float4 acc = make_float4(0.f, 0.f, 0.f, 0.f);
        int c = 0;
        for (; c + 4 <= len; c += 4) {
            int r0 = child[beg+c+0], r1 = child[beg+c+1];
            int r2 = child[beg+c+2], r3 = child[beg+c+3];
            float4 v0 = ((const float4*)(src + (size_t)r0 * Hc))[lane];
            float4 v1 = ((const float4*)(src + (size_t)r1 * Hc))[lane];
            float4 v2 = ((const float4*)(src + (size_t)r2 * Hc))[lane];
            float4 v3 = ((const float4*)(src + (size_t)r3 * Hc))[lane];
            acc.x += (v0.x + v1.x) + (v2.x + v3.x);
            acc.y += (v0.y + v1.y) + (v2.y + v3.y);
            acc.z += (v0.z + v1.z) + (v2.z + v3.z);
            acc.w += (v0.w + v1.w) + (v2.w + v3.w);
        }
        for (; c < len; ++c) {
            int r0 = child[beg + c];
            float4 v0 = ((const float4*)(src + (size_t)r0 * Hc))[lane];
            acc.x += v0.x; acc.y += v0.y; acc.z += v0.z; acc.w += v0.w;
        }
        ushort4 hv, lv;
        hv.x = f2bf(acc.x); lv.x = f2bf(acc.x - bf2f(hv.x));
        hv.y = f2bf(acc.y); lv.y = f2bf(acc.y - bf2f(hv.y));
        hv.z = f2bf(acc.z); lv.z = f2bf(acc.z - bf2f(hv.z));
        hv.w = f2bf(acc.w); lv.w = f2bf(acc.w - bf2f(hv.w));
        *(ushort4*)(dhi + (size_t)seg * Hc + lane * 4) = hv;
        *(ushort4*)(dlo + (size_t)seg * Hc + lane * 4) = lv;
    }
}

// ---------------------------------------------------------------------------
// Level-1 projection: tree-sorted; ACCUMULATE the 128-vector per task, project
// once per task (linearity), 10 global atomics per task. Pure read-bound.
// ---------------------------------------------------------------------------
__global__ __launch_bounds__(512) void k_proj0(
    const float* __restrict__ src, const int* __restrict__ child,
    const int* __restrict__ off, const int* __restrict__ cnt,
    const float* __restrict__ predW, float* __restrict__ accOut, int chunks)
{
    const int lane = threadIdx.x & 31;
    const int sub  = threadIdx.x >> 5;
    float4 wreg[Cc];
    #pragma unroll
    for (int cc = 0; cc < Cc; cc++) {
        wreg[cc].x = predW[(lane*4 + 0) * Cc + cc];
        wreg[cc].y = predW[(lane*4 + 1) * Cc + cc];
        wreg[cc].z = predW[(lane*4 + 2) * Cc + cc];
        wreg[cc].w = predW[(lane*4 + 3) * Cc + cc];
    }
    const int ntask = Bc * chunks;
    for (int t = blockIdx.x * 16 + sub; t < ntask; t += gridDim.x * 16) {
        const int tr = t & (Bc - 1);
        const int ch = t >> 9;
        const int beg = off[tr], len = cnt[tr];
        int c0 = (int)(((long long)len * ch) / chunks);
        int c1 = (int)(((long long)len * (ch + 1)) / chunks);
        float4 acc = make_float4(0.f, 0.f, 0.f, 0.f);
        int c = c0;
        for (; c + 2 <= c1; c += 2) {
            int r0 = child[beg+c+0], r1 = child[beg+c+1];
            float4 v0 = ((const float4*)(src + (size_t)r0 * Hc))[lane];
            float4 v1 = ((const float4*)(src + (size_t)r1 * Hc))[lane];
            acc.x += v0.x + v1.x; acc.y += v0.y + v1.y;
            acc.z += v0.z + v1.z; acc.w += v0.w + v1.w;
        }
        if (c < c1) {
            int r0 = child[beg + c];
            float4 v0 = ((const float4*)(src + (size_t)r0 * Hc))[lane];
            acc.x += v0.x; acc.y += v0.y; acc.z += v0.z; acc.w += v0.w;
        }
        float pv[Cc];
        #pragma unroll
        for (int cc = 0; cc < Cc; cc++) {
            pv[cc] = acc.x * wreg[cc].x + acc.y * wreg[cc].y
                   + acc.z * wreg[cc].z + acc.w * wreg[cc].w;
        }
        #pragma unroll
        for (int o = 16; o; o >>= 1) {
            #pragma unroll
            for (int cc = 0; cc < Cc; cc++) pv[cc] += __shfl_xor(pv[cc], o, 32);
        }
        if (lane == 0) {
            #pragma unroll
            for (int cc = 0; cc < Cc; cc++) atomicAdd(&accOut[tr * Cc + cc], pv[cc]);
        }
    }
}

// ---------------------------------------------------------------------------
// Split-bf16 MFMA GEMM, in-place on (Ahi,Alo): t = f(A) @ W + bias.
// BN_IN=0: A used as-is (hi/lo are a split of fp32). BN_IN=1: reconstruct
// x=hi+lo, y=relu(x*scale+shift), re-split. 3-term MFMA: err ~2^-18.
// Accumulates column sum/sumsq of OUTPUT (incl bias) into ssum/ssq.
// Block 256 = 4 waves x 16 rows; grid = M/64.
// ---------------------------------------------------------------------------
template<int BN_IN>
__global__ __launch_bounds__(256) void k_gemm_mfma(
    u16* __restrict__ Ahi, u16* __restrict__ Alo,
    const float* __restrict__ W, const float* __restrict__ bias,
    const float* __restrict__ scale, const float* __restrict__ shift,
    float* __restrict__ ssum, float* __restrict__ ssq)
{
    __shared__ __align__(16) u16 Wh[128 * 136];   // [n][k] transposed, padded
    __shared__ __align__(16) u16 Wl[128 * 136];
    __shared__ float bl[128], scl[128], shl[128];
    __shared__ float lsum[128], lsq[128];

    const int tid = threadIdx.x;
    for (int i = tid; i < 128 * 128; i += 256) {
        int k = i >> 7, n = i & 127;
        float f = W[i];
        u16 h = f2bf(f);
        Wh[n * 136 + k] = h;
        Wl[n * 136 + k] = f2bf(f - bf2f(h));
    }
    if (tid < 128) {
        bl[tid] = bias[tid];
        lsum[tid] = 0.f; lsq[tid] = 0.f;
        if (BN_IN) { scl[tid] = scale[tid]; shl[tid] = shift[tid]; }
    }
    __syncthreads();

    const int wave = tid >> 6;
    const int l    = tid & 63;
    const int r16  = l & 15;
    const int kg   = l >> 4;
    const int row0 = blockIdx.x * 64 + wave * 16;

    const u16* arow_h = Ahi + (size_t)(row0 + r16) * 128 + kg * 8;
    const u16* arow_l = Alo + (size_t)(row0 + r16) * 128 + kg * 8;

    f32x4 acc[8];
    #pragma unroll
    for (int nt = 0; nt < 8; nt++) acc[nt] = (f32x4){0.f, 0.f, 0.f, 0.f};

    #pragma unroll
    for (int kk = 0; kk < 4; kk++) {
        bf16x8 ah, al;
        bf16x8 rh = *(const bf16x8*)(arow_h + kk * 32);
        bf16x8 rl = *(const bf16x8*)(arow_l + kk * 32);
        if (BN_IN == 0) {
            ah = rh; al = rl;
        } else {
            const int kb = kk * 32 + kg * 8;
            #pragma unroll
            for (int j = 0; j < 8; j++) {
                float x = bf2f((u16)rh[j]) + bf2f((u16)rl[j]);
                float y = fmaxf(fmaf(x, scl[kb + j], shl[kb + j]), 0.f);
                u16 yh = f2bf(y);
                ah[j] = (short)yh;
                al[j] = (short)f2bf(y - bf2f(yh));
            }
        }
        #pragma unroll
        for (int nt = 0; nt < 8; nt++) {
            const int bo = (nt * 16 + r16) * 136 + kk * 32 + kg * 8;
            bf16x8 bh = *(const bf16x8*)(Wh + bo);
            bf16x8 bw = *(const bf16x8*)(Wl + bo);
            acc[nt] = __builtin_amdgcn_mfma_f32_16x16x32_bf16(ah, bh, acc[nt], 0, 0, 0);
            acc[nt] = __builtin_amdgcn_mfma_f32_16x16x32_bf16(ah, bw, acc[nt], 0, 0, 0);
            acc[nt] = __builtin_amdgcn_mfma_f32_16x16x32_bf16(al, bh, acc[nt], 0, 0, 0);
        }
    }

    // epilogue: bias + stats (C/D layout: col = l&15, row = (l>>4)*4 + j)
    float v[8][4];
    #pragma unroll
    for (int nt = 0; nt < 8; nt++) {
        float b = bl[nt * 16 + r16];
        float s = 0.f, q = 0.f;
        #pragma unroll
        for (int j = 0; j < 4; j++) {
            float x = acc[nt][j] + b;
            v[nt][j] = x;
            s += x; q += x * x;
        }
        s += __shfl_xor(s, 16); s += __shfl_xor(s, 32);
        q += __shfl_xor(q, 16); q += __shfl_xor(q, 32);
        if (kg == 0) {
            atomicAdd(&lsum[nt * 16 + r16], s);
            atomicAdd(&lsq [nt * 16 + r16], q);
        }
    }
    __syncthreads();                 // all waves done reading Wh/Wl
    #pragma unroll
    for (int nt = 0; nt < 8; nt++) {
        #pragma unroll
        for (int j = 0; j < 4; j++) {
            int rl_ = wave * 16 + kg * 4 + j;
            int c   = nt * 16 + r16;
            float x = v[nt][j];
            u16 hh = f2bf(x);
            Wh[rl_ * 128 + c] = hh;
            Wl[rl_ * 128 + c] = f2bf(x - bf2f(hh));
        }
    }
    __syncthreads();
    {
        uint4* gh = (uint4*)(Ahi + (size_t)blockIdx.x * 64 * 128);
        uint4* gl = (uint4*)(Alo + (size_t)blockIdx.x * 64 * 128);
        const uint4* sh4 = (const uint4*)Wh;
        const uint4* sl4 = (const uint4*)Wl;
        for (int i = tid; i < 64 * 128 / 8; i += 256) {
            gh[i] = sh4[i];
            gl[i] = sl4[i];
        }
    }
    if (tid < 128) {
        atomicAdd(&ssum[tid], lsum[tid]);
        atomicAdd(&ssq [tid], lsq [tid]);
    }
}

// ---------------------------------------------------------------------------
// Level-2 gather: split-bf16 t4 + BN+ReLU -> p2 (fp32, chunked atomics).
// ---------------------------------------------------------------------------
__global__ __launch_bounds__(512) void k_gather2(
    const u16* __restrict__ shi, const u16* __restrict__ slo,
    const int* __restrict__ child, const int* __restrict__ off,
    const int* __restrict__ cnt, const float* __restrict__ scale,
    const float* __restrict__ shift, float* __restrict__ dst,
    int nseg, int chunks)
{
    const int lane = threadIdx.x & 31;
    const int sub  = threadIdx.x >> 5;
    float4 sc4 = ((const float4*)scale)[lane];
    float4 sh4 = ((const float4*)shift)[lane];

    const int ntask = nseg * chunks;
    for (int t = blockIdx.x * 16 + sub; t < ntask; t += gridDim.x * 16) {
        const int seg = t % nseg;
        const int ch  = t / nseg;
        const int beg = off[seg], len = cnt[seg];
        int c0 = (int)(((long long)len * ch) / chunks);
        int c1 = (int)(((long long)len * (ch + 1)) / chunks);
        float4 acc = make_float4(0.f, 0.f, 0.f, 0.f);
        for (int c = c0; c < c1; ++c) {
            int r0 = child[beg + c];
            ushort4 h = *(const ushort4*)(shi + (size_t)r0 * Hc + lane * 4);
            ushort4 lo = *(const ushort4*)(slo + (size_t)r0 * Hc + lane * 4);
            acc.x += fmaxf(fmaf(bf2f(h.x)+bf2f(lo.x), sc4.x, sh4.x), 0.f);
            acc.y += fmaxf(fmaf(bf2f(h.y)+bf2f(lo.y), sc4.y, sh4.y), 0.f);
            acc.z += fmaxf(fmaf(bf2f(h.z)+bf2f(lo.z), sc4.z, sh4.z), 0.f);
            acc.w += fmaxf(fmaf(bf2f(h.w)+bf2f(lo.w), sc4.w, sh4.w), 0.f);
        }
        float* d = dst + (size_t)seg * Hc + lane * 4;
        atomicAdd(d + 0, acc.x);
        atomicAdd(d + 1, acc.y);
        atomicAdd(d + 2, acc.z);
        atomicAdd(d + 3, acc.w);
    }
}

// ---------------------------------------------------------------------------
// Level-2 projection: split-bf16 t4 + BN+ReLU per row, accumulate vector,
// project once per task onto predW rows [128..255].
// ---------------------------------------------------------------------------
__global__ __launch_bounds__(512) void k_proj1(
    const u16* __restrict__ shi, const u16* __restrict__ slo,
    const int* __restrict__ child, const int* __restrict__ off,
    const int* __restrict__ cnt, const float* __restrict__ predW,
    const float* __restrict__ scale, const float* __restrict__ shift,
    float* __restrict__ accOut, int chunks)
{
    const int lane = threadIdx.x & 31;
    const int sub  = threadIdx.x >> 5;
    float4 wreg[Cc];
    #pragma unroll
    for (int cc = 0; cc < Cc; cc++) {
        wreg[cc].x = predW[(Hc + lane*4 + 0) * Cc + cc];
        wreg[cc].y = predW[(Hc + lane*4 + 1) * Cc + cc];
        wreg[cc].z = predW[(Hc + lane*4 + 2) * Cc + cc];
        wreg[cc].w = predW[(Hc + lane*4 + 3) * Cc + cc];
    }
    float4 sc4 = ((const float4*)scale)[lane];
    float4 sh4 = ((const float4*)shift)[lane];

    const int ntask = Bc * chunks;
    for (int t = blockIdx.x * 16 + sub; t < ntask; t += gridDim.x * 16) {
        const int tr = t & (Bc - 1);
        const int ch = t >> 9;
        const int beg = off[tr], len = cnt[tr];
        int c0 = (int)(((long long)len * ch) / chunks);
        int c1 = (int)(((long long)len * (ch + 1)) / chunks);
        float4 acc = make_float4(0.f, 0.f, 0.f, 0.f);
        for (int c = c0; c < c1; ++c) {
            int r0 = child[beg + c];
            ushort4 h = *(const ushort4*)(shi + (size_t)r0 * Hc + lane * 4);
            ushort4 lo = *(const ushort4*)(slo + (size_t)r0 * Hc + lane * 4);
            acc.x += fmaxf(fmaf(bf2f(h.x)+bf2f(lo.x), sc4.x, sh4.x), 0.f);
            acc.y += fmaxf(fmaf(bf2f(h.y)+bf2f(lo.y), sc4.y, sh4.y), 0.f);
            acc.z += fmaxf(fmaf(bf2f(h.z)+bf2f(lo.z), sc4.z, sh4.z), 0.f);
            acc.w += fmaxf(fmaf(bf2f(h.w)+bf2f(lo.w), sc4.w, sh4.w), 0.f);
        }
        float pv[Cc];
        #pragma unroll
        for (int cc = 0; cc < Cc; cc++) {
            pv[cc] = acc.x * wreg[cc].x + acc.y * wreg[cc].y
                   + acc.z * wreg[cc].z + acc.w * wreg[cc].w;
        }
        #pragma unroll
        for (int o = 16; o; o >>= 1) {
            #pragma unroll
            for (int cc = 0; cc < Cc; cc++) pv[cc] += __shfl_xor(pv[cc], o, 32);
        }
        if (lane == 0) {
            #pragma unroll
            for (int cc = 0; cc < Cc; cc++) atomicAdd(&accOut[tr * Cc + cc], pv[cc]);
        }
    }
}

// ---------------------------------------------------------------------------
// fp32 GEMM for the tiny level-2 MLP (unchanged).
// ---------------------------------------------------------------------------
__global__ __launch_bounds__(256) void k_gemm(
    const float* __restrict__ in, float* __restrict__ out,
    const float* __restrict__ W, const float* __restrict__ bias,
    const float* __restrict__ scale, const float* __restrict__ shift,
    float* __restrict__ ssum, float* __restrict__ ssq, int M)
{
    __shared__ float Wlds[Hc * Hc];
    __shared__ float inl[32 * Hc];

    const int tid = threadIdx.x;
    {
        const float4* W4 = (const float4*)W;
        float4* Wl4 = (float4*)Wlds;
        for (int i = tid; i < Hc * Hc / 4; i += 256) Wl4[i] = W4[i];
    }
    const int row0 = blockIdx.x * 32;
    const bool bn = (scale != nullptr);
    for (int i = tid; i < 32 * 32; i += 256) {
        int r = i >> 5, g = i & 31;
        float4 v = ((const float4*)(in + (size_t)(row0 + r) * Hc))[g];
        if (bn) {
            float4 sc = ((const float4*)scale)[g];
            float4 sh = ((const float4*)shift)[g];
            v.x = fmaxf(v.x * sc.x + sh.x, 0.f);
            v.y = fmaxf(v.y * sc.y + sh.y, 0.f);
            v.z = fmaxf(v.z * sc.z + sh.z, 0.f);
            v.w = fmaxf(v.w * sc.w + sh.w, 0.f);
        }
        ((float4*)(inl + r * Hc))[g] = v;
    }
    __syncthreads();

    const int rg = tid >> 5;
    const int cg = tid & 31;
    float acc[4][4] = {{0.f}};
    for (int k = 0; k < Hc; k += 4) {
        float a[4][4], w[4][4];
        #pragma unroll
        for (int r = 0; r < 4; r++) {
            float4 t = *(const float4*)&inl[(rg*4 + r) * Hc + k];
            a[r][0] = t.x; a[r][1] = t.y; a[r][2] = t.z; a[r][3] = t.w;
        }
        #pragma unroll
        for (int kk = 0; kk < 4; kk++) {
            float4 t = *(const float4*)&Wlds[(k + kk) * Hc + cg*4];
            w[kk][0] = t.x; w[kk][1] = t.y; w[kk][2] = t.z; w[kk][3] = t.w;
        }
        #pragma unroll
        for (int r = 0; r < 4; r++)
            #pragma unroll
            for (int kk = 0; kk < 4; kk++)
                #pragma unroll
                for (int c = 0; c < 4; c++)
                    acc[r][c] = fmaf(a[r][kk], w[kk][c], acc[r][c]);
    }

    float b4[4];
    #pragma unroll
    for (int c = 0; c < 4; c++) b4[c] = bias[cg*4 + c];
    float s[4] = {0.f,0.f,0.f,0.f}, q[4] = {0.f,0.f,0.f,0.f};
    #pragma unroll
    for (int r = 0; r < 4; r++) {
        float v0 = acc[r][0] + b4[0];
        float v1 = acc[r][1] + b4[1];
        float v2 = acc[r][2] + b4[2];
        float v3 = acc[r][3] + b4[3];
        float4 o; o.x = v0; o.y = v1; o.z = v2; o.w = v3;
        s[0] += v0; s[1] += v1; s[2] += v2; s[3] += v3;
        q[0] += v0*v0; q[1] += v1*v1; q[2] += v2*v2; q[3] += v3*v3;
        *(float4*)&out[(size_t)(row0 + rg*4 + r) * Hc + cg*4] = o;
    }

    __syncthreads();
    #pragma unroll
    for (int c = 0; c < 4; c++) inl[rg * Hc + cg*4 + c] = s[c];
    __syncthreads();
    if (tid < Hc) {
        float t = 0.f;
        #pragma unroll
        for (int g = 0; g < 8; g++) t += inl[g * Hc + tid];
        atomicAdd(&ssum[tid], t);
    }
    __syncthreads();
    #pragma unroll
    for (int c = 0; c < 4; c++) inl[rg * Hc + cg*4 + c] = q[c];
    __syncthreads();
    if (tid < Hc) {
        float t = 0.f;
        #pragma unroll
        for (int g = 0; g < 8; g++) t += inl[g * Hc + tid];
        atomicAdd(&ssq[tid], t);
    }
}

__global__ __launch_bounds__(128) void k_fin(
    const float* __restrict__ sum, const float* __restrict__ sq,
    const float* __restrict__ g, const float* __restrict__ b,
    float* __restrict__ scale, float* __restrict__ shift, float invN)
{
    int t = threadIdx.x;
    float m = sum[t] * invN;
    float v = sq[t] * invN - m * m;
    float s = g[t] * rsqrtf(v + EPSc);
    scale[t] = s;
    shift[t] = b[t] - m * s;
}

__global__ __launch_bounds__(128) void k_final(
    const float* __restrict__ u2, const float* __restrict__ scaleD,
    const float* __restrict__ shiftD, const float* __restrict__ acc0,
    const float* __restrict__ acc1, const float* __restrict__ predW,
    const float* __restrict__ predb, float* __restrict__ out)
{
    __shared__ float h[Hc];
    __shared__ float wl[Hc * Cc];
    __shared__ float lg[Cc], ex[Cc];
    int b = blockIdx.x, t = threadIdx.x;
    for (int i = t; i < Hc * Cc; i += 128) wl[i] = predW[(2*Hc) * Cc + i];
    float x = u2[(size_t)b * Hc + t];
    h[t] = fmaxf(x * scaleD[t] + shiftD[t], 0.f);
    __syncthreads();
    if (t < Cc) {
        float s = predb[t] + acc0[b * Cc + t] + acc1[b * Cc + t];
        for (int d = 0; d < Hc; d++) s += h[d] * wl[d * Cc + t];
        lg[t] = s;
    }
    __syncthreads();
    if (t < Cc) {
        float m = lg[0];
        #pragma unroll
        for (int c = 1; c < Cc; c++) m = fmaxf(m, lg[c]);
        ex[t] = expf(lg[t] - m);
    }
    __syncthreads();
    if (t < Cc) {
        float s = 0.f;
        #pragma unroll
        for (int c = 0; c < Cc; c++) s += ex[c];
        out[b * Cc + t] = ex[t] / s;
    }
}

extern "C" void kernel_launch(void* const* d_in, const int* in_sizes, int n_in,
                              void* d_out, int out_size, void* d_ws, size_t ws_size,
                              hipStream_t stream) {
    const float* h0      = (const float*)d_in[0];
    const int*   parent1 = (const int*)d_in[1];
    const int*   parent2 = (const int*)d_in[2];
    const int*   tree0   = (const int*)d_in[3];
    const int*   tree1   = (const int*)d_in[4];
    const float* m1W1 = (const float*)d_in[5];
    const float* m1b1 = (const float*)d_in[6];
    const float* m1bng = (const float*)d_in[7];
    const float* m1bnb = (const float*)d_in[8];
    const float* m1W2 = (const float*)d_in[9];
    const float* m1b2 = (const float*)d_in[10];
    const float* bn1g = (const float*)d_in[11];
    const float* bn1b = (const float*)d_in[12];
    const float* m2W1 = (const float*)d_in[13];
    const float* m2b1 = (const float*)d_in[14];
    const float* m2bng = (const float*)d_in[15];
    const float* m2bnb = (const float*)d_in[16];
    const float* m2W2 = (const float*)d_in[17];
    const float* m2b2 = (const float*)d_in[18];
    const float* bn2g = (const float*)d_in[19];
    const float* bn2b = (const float*)d_in[20];
    const float* predW = (const float*)d_in[21];
    const float* predb = (const float*)d_in[22];
    float* out = (float*)d_out;

    // ---- workspace layout ----
    u16* phi = (u16*)d_ws;                              // N1*128 u16 (p1->t1->t4 hi)
    u16* plo = phi + (size_t)N1c * Hc;                  // N1*128 u16 (lo)
    float* fbase = (float*)(plo + (size_t)N1c * Hc);
    float* p2    = fbase;                               // 512*128
    float* u1    = p2 + Bc * Hc;
    float* u2    = u1 + Bc * Hc;
    float* acc0  = u2 + Bc * Hc;                        // 5120
    float* acc1  = acc0 + Bc * Cc;                      // 5120
    float* stats = acc1 + Bc * Cc;                      // 8*128
    float* coeff = stats + 8 * Hc;                      // 8*128
    int* ints   = (int*)(coeff + 8 * Hc);
    int* cnt1   = ints;                  // 131072
    int* off1   = cnt1 + N1c;            // 131072
    int* cur1   = off1 + N1c;            // 131072
    int* cntT0  = cur1 + N1c;            // 512 (small block start)
    int* offT0  = cntT0 + Bc;
    int* curT0  = offT0 + Bc;
    int* cnt2   = curT0 + Bc;
    int* off2   = cnt2 + Bc;
    int* cur2   = off2 + Bc;
    int* cntT1  = cur2 + Bc;
    int* offT1  = cntT1 + Bc;
    int* curT1  = offT1 + Bc;
    int* bsum   = curT1 + Bc;            // 512 (end of small block: 10*512)
    int* child1 = bsum + Bc;             // 524288
    int* childT0= child1 + N0c;          // 524288
    int* child2 = childT0 + N0c;         // 131072
    int* childT1= child2 + N1c;          // 131072

    float* sumA = stats + 0 * Hc; float* sqA = stats + 1 * Hc;
    float* sumB = stats + 2 * Hc; float* sqB = stats + 3 * Hc;
    float* sumC = stats + 4 * Hc; float* sqC = stats + 5 * Hc;
    float* sumD = stats + 6 * Hc; float* sqD = stats + 7 * Hc;
    float* scaleA = coeff + 0 * Hc; float* shiftA = coeff + 1 * Hc;
    float* scaleB = coeff + 2 * Hc; float* shiftB = coeff + 3 * Hc;
    float* scaleC = coeff + 4 * Hc; float* shiftC = coeff + 5 * Hc;
    float* scaleD = coeff + 6 * Hc; float* shiftD = coeff + 7 * Hc;

    // ---- zero counters / accumulators ----
    hipMemsetAsync(cnt1, 0, 3 * (size_t)N1c * sizeof(int), stream);
    hipMemsetAsync(cntT0, 0, 10 * Bc * sizeof(int), stream);
    hipMemsetAsync(p2, 0, (size_t)Bc * Hc * sizeof(float), stream);
    hipMemsetAsync(acc0, 0, (2 * Bc * Cc + 8 * Hc) * sizeof(float), stream);

    // ---- counting sorts ----
    k_count_pair<<<512, 256, 0, stream>>>(parent1, cnt1, tree0, cntT0, N0c);
    k_count512<<<128, 256, 0, stream>>>(parent2, cnt2, N1c);
    k_count512<<<128, 256, 0, stream>>>(tree1, cntT1, N1c);

    k_scan_local<<<N1c / 256, 256, 0, stream>>>(cnt1, off1, bsum, N1c);
    k_scan_sums<<<1, 512, 0, stream>>>(bsum, N1c / 256);
    k_scan_add<<<N1c / 256, 256, 0, stream>>>(off1, bsum, N1c);
    k_scan512<<<1, 512, 0, stream>>>(cntT0, offT0);
    k_scan512<<<1, 512, 0, stream>>>(cnt2, off2);
    k_scan512<<<1, 512, 0, stream>>>(cntT1, offT1);

    k_place<<<N0c / 256, 256, 0, stream>>>(parent1, off1, cur1, child1, N0c);
    k_place_bin<<<(N0c + PB_CH - 1) / PB_CH, 1024, 0, stream>>>(tree0, offT0, curT0, childT0, N0c);
    k_place_bin<<<(N1c + PB_CH - 1) / PB_CH, 1024, 0, stream>>>(parent2, off2, cur2, child2, N1c);
    k_place_bin<<<(N1c + PB_CH - 1) / PB_CH, 1024, 0, stream>>>(tree1, offT1, curT1, childT1, N1c);

    // ---- level 1: p1 gather (split-bf16) + g0 projection ----
    k_gather_split<<<4096, 512, 0, stream>>>(h0, child1, off1, cnt1, phi, plo, N1c);
    k_proj0<<<1024, 512, 0, stream>>>(h0, childT0, offT0, cntT0, predW, acc0, 32);

    // ---- layer-1 MLP via split-bf16 MFMA (in place on phi/plo) ----
    k_gemm_mfma<0><<<N1c / 64, 256, 0, stream>>>(phi, plo, m1W1, m1b1,
                                                 nullptr, nullptr, sumA, sqA);
    k_fin<<<1, 128, 0, stream>>>(sumA, sqA, m1bng, m1bnb, scaleA, shiftA, 1.f / N1c);
    k_gemm_mfma<1><<<N1c / 64, 256, 0, stream>>>(phi, plo, m1W2, m1b2,
                                                 scaleA, shiftA, sumB, sqB);
    k_fin<<<1, 128, 0, stream>>>(sumB, sqB, bn1g, bn1b, scaleB, shiftB, 1.f / N1c);

    // ---- level 2: p2 gather + g1 projection (BN-B + ReLU on load) ----
    k_gather2<<<512, 512, 0, stream>>>(phi, plo, child2, off2, cnt2,
                                       scaleB, shiftB, p2, Bc, 16);
    k_proj1<<<512, 512, 0, stream>>>(phi, plo, childT1, offT1, cntT1, predW,
                                     scaleB, shiftB, acc1, 16);

    // ---- layer-2 MLP + final ----
    k_gemm<<<Bc / 32, 256, 0, stream>>>(p2, u1, m2W1, m2b1, nullptr, nullptr,
                                        sumC, sqC, Bc);
    k_fin<<<1, 128, 0, stream>>>(sumC, sqC, m2bng, m2bnb, scaleC, shiftC, 1.f / Bc);
    k_gemm<<<Bc / 32, 256, 0, stream>>>(u1, u2, m2W2, m2b2, scaleC, shiftC,
                                        sumD, sqD, Bc);
    k_fin<<<1, 128, 0, stream>>>(sumD, sqD, bn2g, bn2b, scaleD, shiftD, 1.f / Bc);
    k_final<<<Bc, 128, 0, stream>>>(u2, scaleD, shiftD, acc0, acc1, predW, predb, out);
}

// Round 6
// 446.104 us; speedup vs baseline: 3.2697x; 1.1089x over previous
//
#include <hip/hip_runtime.h>

#define N0c 524288
#define N1c 131072
#define Bc  512
#define Dc  128
#define Hc  128
#define Cc  10
#define EPSc 1e-5f
#define PB_CH 4096

typedef unsigned short u16;
typedef __attribute__((ext_vector_type(8))) short bf16x8;
typedef __attribute__((ext_vector_type(4))) float f32x4;

__device__ __forceinline__ u16 f2bf(float f) {
    unsigned u = __builtin_bit_cast(unsigned, f);
    unsigned r = (u + 0x7fffu + ((u >> 16) & 1u)) >> 16;
    return (u16)r;
}
__device__ __forceinline__ float bf2f(u16 h) {
    return __builtin_bit_cast(float, (unsigned)h << 16);
}

// ---------------------------------------------------------------------------
// Fused histograms: blocks [0,512) read parent1 (direct atomics, ~4-way) +
// tree0 (LDS hist); blocks [512,640) read parent2 + tree1 (two LDS hists).
// ---------------------------------------------------------------------------
__global__ __launch_bounds__(256) void k_count_all(
    const int* __restrict__ parent1, int* __restrict__ cnt1,
    const int* __restrict__ tree0, int* __restrict__ cntT0,
    const int* __restrict__ parent2, int* __restrict__ cnt2,
    const int* __restrict__ tree1, int* __restrict__ cntT1)
{
    __shared__ int hA[Bc], hB[Bc];
    const int b = blockIdx.x, tid = threadIdx.x;
    if (b < 512) {
        for (int i = tid; i < Bc; i += 256) hA[i] = 0;
        __syncthreads();
        for (int i = b * 256 + tid; i < N0c; i += 512 * 256) {
            atomicAdd(&cnt1[parent1[i]], 1);
            atomicAdd(&hA[tree0[i]], 1);
        }
        __syncthreads();
        for (int i = tid; i < Bc; i += 256) {
            int v = hA[i];
            if (v) atomicAdd(&cntT0[i], v);
        }
    } else {
        for (int i = tid; i < Bc; i += 256) { hA[i] = 0; hB[i] = 0; }
        __syncthreads();
        for (int i = (b - 512) * 256 + tid; i < N1c; i += 128 * 256) {
            atomicAdd(&hA[parent2[i]], 1);
            atomicAdd(&hB[tree1[i]], 1);
        }
        __syncthreads();
        for (int i = tid; i < Bc; i += 256) {
            int v = hA[i]; if (v) atomicAdd(&cnt2[i], v);
            v = hB[i];     if (v) atomicAdd(&cntT1[i], v);
        }
    }
}

__global__ __launch_bounds__(256) void k_scan_local(const int* __restrict__ cnt,
                                                    int* __restrict__ off,
                                                    int* __restrict__ bsum, int n)
{
    __shared__ int s[256];
    int t = threadIdx.x;
    int i = blockIdx.x * 256 + t;
    int v = (i < n) ? cnt[i] : 0;
    s[t] = v; __syncthreads();
    for (int o = 1; o < 256; o <<= 1) {
        int x = (t >= o) ? s[t - o] : 0;
        __syncthreads();
        s[t] += x;
        __syncthreads();
    }
    if (i < n) off[i] = s[t] - v;
    if (t == 255) bsum[blockIdx.x] = s[255];
}

// block 0: exclusive-scan bsum[512]; blocks 1..3: the three 512-bin scans.
__global__ __launch_bounds__(512) void k_scan_sums4(
    int* __restrict__ bsum,
    const int* __restrict__ cntT0, int* __restrict__ offT0,
    const int* __restrict__ cnt2,  int* __restrict__ off2,
    const int* __restrict__ cntT1, int* __restrict__ offT1)
{
    __shared__ int s[512];
    int t = threadIdx.x;
    const int* src; int* dst;
    if (blockIdx.x == 0)      { src = bsum;  dst = bsum;  }
    else if (blockIdx.x == 1) { src = cntT0; dst = offT0; }
    else if (blockIdx.x == 2) { src = cnt2;  dst = off2;  }
    else                      { src = cntT1; dst = offT1; }
    int v = src[t];
    s[t] = v; __syncthreads();
    for (int o = 1; o < 512; o <<= 1) {
        int x = (t >= o) ? s[t - o] : 0;
        __syncthreads();
        s[t] += x;
        __syncthreads();
    }
    dst[t] = s[t] - v;
}

__global__ __launch_bounds__(256) void k_scan_add(int* __restrict__ off,
                                                  const int* __restrict__ bsum, int n)
{
    int i = blockIdx.x * 256 + threadIdx.x;
    if (i < n) off[i] += bsum[blockIdx.x];
}

// ---------------------------------------------------------------------------
// Fused placement: blocks [0,512) direct-place parent1; [512,640) binned
// tree0; [640,672) binned parent2; [672,704) binned tree1.
// ---------------------------------------------------------------------------
__device__ __forceinline__ void place_binned(
    const int* __restrict__ idx, const int* __restrict__ off,
    int* __restrict__ cur, int* __restrict__ child, int n,
    int cb, int* h, int* base)
{
    const int tid = threadIdx.x;
    const int c0 = cb * PB_CH;
    const int c1 = min(c0 + PB_CH, n);
    for (int i = tid; i < Bc; i += 1024) h[i] = 0;
    __syncthreads();
    for (int i = c0 + tid; i < c1; i += 1024)
        atomicAdd(&h[idx[i]], 1);
    __syncthreads();
    for (int i = tid; i < Bc; i += 1024) {
        int v = h[i];
        base[i] = v ? atomicAdd(&cur[i], v) : 0;
    }
    __syncthreads();
    for (int i = tid; i < Bc; i += 1024) h[i] = 0;
    __syncthreads();
    for (int i = c0 + tid; i < c1; i += 1024) {
        int b = idx[i];
        int p = atomicAdd(&h[b], 1);
        child[off[b] + base[b] + p] = i;
    }
}

__global__ __launch_bounds__(1024) void k_place_all(
    const int* __restrict__ parent1, const int* __restrict__ off1,
    int* __restrict__ cur1, int* __restrict__ child1,
    const int* __restrict__ tree0, const int* __restrict__ offT0,
    int* __restrict__ curT0, int* __restrict__ childT0,
    const int* __restrict__ parent2, const int* __restrict__ off2,
    int* __restrict__ cur2, int* __restrict__ child2,
    const int* __restrict__ tree1, const int* __restrict__ offT1,
    int* __restrict__ curT1, int* __restrict__ childT1)
{
    __shared__ int h[Bc], base[Bc];
    const int b = blockIdx.x;
    if (b < 512) {
        int r = b * 1024 + threadIdx.x;   // 512*1024 == N0c exactly
        int p = parent1[r];
        int pos = off1[p] + atomicAdd(&cur1[p], 1);
        child1[pos] = r;
    } else if (b < 640) {
        place_binned(tree0, offT0, curT0, childT0, N0c, b - 512, h, base);
    } else if (b < 672) {
        place_binned(parent2, off2, cur2, child2, N1c, b - 640, h, base);
    } else {
        place_binned(tree1, offT1, curT1, childT1, N1c, b - 672, h, base);
    }
}

// ---------------------------------------------------------------------------
// Fused level-1 pass over h0: blocks [0,4096) = parent-sorted gather into
// split-bf16 p1; blocks [4096,5120) = tree-sorted accumulate+project -> acc0.
// ---------------------------------------------------------------------------
__global__ __launch_bounds__(512) void k_l1(
    const float* __restrict__ src,
    const int* __restrict__ child1, const int* __restrict__ off1,
    const int* __restrict__ cnt1,
    const int* __restrict__ childT0, const int* __restrict__ offT0,
    const int* __restrict__ cntT0,
    const float* __restrict__ predW,
    u16* __restrict__ dhi, u16* __restrict__ dlo, float* __restrict__ accOut)
{
    const int lane = threadIdx.x & 31;
    const int sub  = threadIdx.x >> 5;

    if (blockIdx.x < 4096) {
        // ---- gather role ----
        for (int seg = blockIdx.x * 16 + sub; seg < N1c; seg += 4096 * 16) {
            const int beg = off1[seg], len = cnt1[seg];
            float4 acc = make_float4(0.f, 0.f, 0.f, 0.f);
            int c = 0;
            for (; c + 4 <= len; c += 4) {
                int r0 = child1[beg+c+0], r1 = child1[beg+c+1];
                int r2 = child1[beg+c+2], r3 = child1[beg+c+3];
                float4 v0 = ((const float4*)(src + (size_t)r0 * Hc))[lane];
                float4 v1 = ((const float4*)(src + (size_t)r1 * Hc))[lane];
                float4 v2 = ((const float4*)(src + (size_t)r2 * Hc))[lane];
                float4 v3 = ((const float4*)(src + (size_t)r3 * Hc))[lane];
                acc.x += (v0.x + v1.x) + (v2.x + v3.x);
                acc.y += (v0.y + v1.y) + (v2.y + v3.y);
                acc.z += (v0.z + v1.z) + (v2.z + v3.z);
                acc.w += (v0.w + v1.w) + (v2.w + v3.w);
            }
            for (; c < len; ++c) {
                int r0 = child1[beg + c];
                float4 v0 = ((const float4*)(src + (size_t)r0 * Hc))[lane];
                acc.x += v0.x; acc.y += v0.y; acc.z += v0.z; acc.w += v0.w;
            }
            ushort4 hv, lv;
            hv.x = f2bf(acc.x); lv.x = f2bf(acc.x - bf2f(hv.x));
            hv.y = f2bf(acc.y); lv.y = f2bf(acc.y - bf2f(hv.y));
            hv.z = f2bf(acc.z); lv.z = f2bf(acc.z - bf2f(hv.z));
            hv.w = f2bf(acc.w); lv.w = f2bf(acc.w - bf2f(hv.w));
            *(ushort4*)(dhi + (size_t)seg * Hc + lane * 4) = hv;
            *(ushort4*)(dlo + (size_t)seg * Hc + lane * 4) = lv;
        }
    } else {
        // ---- projection role (chunks=32) ----
        float4 wreg[Cc];
        #pragma unroll
        for (int cc = 0; cc < Cc; cc++) {
            wreg[cc].x = predW[(lane*4 + 0) * Cc + cc];
            wreg[cc].y = predW[(lane*4 + 1) * Cc + cc];
            wreg[cc].z = predW[(lane*4 + 2) * Cc + cc];
            wreg[cc].w = predW[(lane*4 + 3) * Cc + cc];
        }
        const int t = (blockIdx.x - 4096) * 16 + sub;   // 16384 tasks, 1 each
        const int tr = t & (Bc - 1);
        const int ch = t >> 9;
        const int beg = offT0[tr], len = cntT0[tr];
        int c0 = (int)(((long long)len * ch) / 32);
        int c1 = (int)(((long long)len * (ch + 1)) / 32);
        float4 acc = make_float4(0.f, 0.f, 0.f, 0.f);
        int c = c0;
        for (; c + 2 <= c1; c += 2) {
            int r0 = childT0[beg+c+0], r1 = childT0[beg+c+1];
            float4 v0 = ((const float4*)(src + (size_t)r0 * Hc))[lane];
            float4 v1 = ((const float4*)(src + (size_t)r1 * Hc))[lane];
            acc.x += v0.x + v1.x; acc.y += v0.y + v1.y;
            acc.z += v0.z + v1.z; acc.w += v0.w + v1.w;
        }
        if (c < c1) {
            int r0 = childT0[beg + c];
            float4 v0 = ((const float4*)(src + (size_t)r0 * Hc))[lane];
            acc.x += v0.x; acc.y += v0.y; acc.z += v0.z; acc.w += v0.w;
        }
        float pv[Cc];
        #pragma unroll
        for (int cc = 0; cc < Cc; cc++) {
            pv[cc] = acc.x * wreg[cc].x + acc.y * wreg[cc].y
                   + acc.z * wreg[cc].z + acc.w * wreg[cc].w;
        }
        #pragma unroll
        for (int o = 16; o; o >>= 1) {
            #pragma unroll
            for (int cc = 0; cc < Cc; cc++) pv[cc] += __shfl_xor(pv[cc], o, 32);
        }
        if (lane == 0) {
            #pragma unroll
            for (int cc = 0; cc < Cc; cc++) atomicAdd(&accOut[tr * Cc + cc], pv[cc]);
        }
    }
}

// ---------------------------------------------------------------------------
// Split-bf16 MFMA GEMM, in-place on (Ahi,Alo). BN_IN=1 computes the BN
// scale/shift from batch stats in the prologue (k_fin folded in).
// ---------------------------------------------------------------------------
template<int BN_IN>
__global__ __launch_bounds__(256) void k_gemm_mfma(
    u16* __restrict__ Ahi, u16* __restrict__ Alo,
    const float* __restrict__ W, const float* __restrict__ bias,
    const float* __restrict__ bn_sum, const float* __restrict__ bn_sq,
    const float* __restrict__ bn_g, const float* __restrict__ bn_b, float invN,
    float* __restrict__ ssum, float* __restrict__ ssq)
{
    __shared__ __align__(16) u16 Wh[128 * 136];   // [n][k] transposed, padded
    __shared__ __align__(16) u16 Wl[128 * 136];
    __shared__ float bl[128], scl[128], shl[128];
    __shared__ float lsum[128], lsq[128];

    const int tid = threadIdx.x;
    for (int i = tid; i < 128 * 128; i += 256) {
        int k = i >> 7, n = i & 127;
        float f = W[i];
        u16 h = f2bf(f);
        Wh[n * 136 + k] = h;
        Wl[n * 136 + k] = f2bf(f - bf2f(h));
    }
    if (tid < 128) {
        bl[tid] = bias[tid];
        lsum[tid] = 0.f; lsq[tid] = 0.f;
        if (BN_IN) {
            float m = bn_sum[tid] * invN;
            float v = bn_sq[tid] * invN - m * m;
            float s = bn_g[tid] * rsqrtf(v + EPSc);
            scl[tid] = s;
            shl[tid] = bn_b[tid] - m * s;
        }
    }
    __syncthreads();

    const int wave = tid >> 6;
    const int l    = tid & 63;
    const int r16  = l & 15;
    const int kg   = l >> 4;
    const int row0 = blockIdx.x * 64 + wave * 16;

    const u16* arow_h = Ahi + (size_t)(row0 + r16) * 128 + kg * 8;
    const u16* arow_l = Alo + (size_t)(row0 + r16) * 128 + kg * 8;

    f32x4 acc[8];
    #pragma unroll
    for (int nt = 0; nt < 8; nt++) acc[nt] = (f32x4){0.f, 0.f, 0.f, 0.f};

    #pragma unroll
    for (int kk = 0; kk < 4; kk++) {
        bf16x8 ah, al;
        bf16x8 rh = *(const bf16x8*)(arow_h + kk * 32);
        bf16x8 rl = *(const bf16x8*)(arow_l + kk * 32);
        if (BN_IN == 0) {
            ah = rh; al = rl;
        } else {
            const int kb = kk * 32 + kg * 8;
            #pragma unroll
            for (int j = 0; j < 8; j++) {
                float x = bf2f((u16)rh[j]) + bf2f((u16)rl[j]);
                float y = fmaxf(fmaf(x, scl[kb + j], shl[kb + j]), 0.f);
                u16 yh = f2bf(y);
                ah[j] = (short)yh;
                al[j] = (short)f2bf(y - bf2f(yh));
            }
        }
        #pragma unroll
        for (int nt = 0; nt < 8; nt++) {
            const int bo = (nt * 16 + r16) * 136 + kk * 32 + kg * 8;
            bf16x8 bh = *(const bf16x8*)(Wh + bo);
            bf16x8 bw = *(const bf16x8*)(Wl + bo);
            acc[nt] = __builtin_amdgcn_mfma_f32_16x16x32_bf16(ah, bh, acc[nt], 0, 0, 0);
            acc[nt] = __builtin_amdgcn_mfma_f32_16x16x32_bf16(ah, bw, acc[nt], 0, 0, 0);
            acc[nt] = __builtin_amdgcn_mfma_f32_16x16x32_bf16(al, bh, acc[nt], 0, 0, 0);
        }
    }

    // epilogue: bias + stats (C/D layout: col = l&15, row = (l>>4)*4 + j)
    float v[8][4];
    #pragma unroll
    for (int nt = 0; nt < 8; nt++) {
        float b = bl[nt * 16 + r16];
        float s = 0.f, q = 0.f;
        #pragma unroll
        for (int j = 0; j < 4; j++) {
            float x = acc[nt][j] + b;
            v[nt][j] = x;
            s += x; q += x * x;
        }
        s += __shfl_xor(s, 16); s += __shfl_xor(s, 32);
        q += __shfl_xor(q, 16); q += __shfl_xor(q, 32);
        if (kg == 0) {
            atomicAdd(&lsum[nt * 16 + r16], s);
            atomicAdd(&lsq [nt * 16 + r16], q);
        }
    }
    __syncthreads();                 // all waves done reading Wh/Wl
    #pragma unroll
    for (int nt = 0; nt < 8; nt++) {
        #pragma unroll
        for (int j = 0; j < 4; j++) {
            int rl_ = wave * 16 + kg * 4 + j;
            int c   = nt * 16 + r16;
            float x = v[nt][j];
            u16 hh = f2bf(x);
            Wh[rl_ * 128 + c] = hh;
            Wl[rl_ * 128 + c] = f2bf(x - bf2f(hh));
        }
    }
    __syncthreads();
    {
        uint4* gh = (uint4*)(Ahi + (size_t)blockIdx.x * 64 * 128);
        uint4* gl = (uint4*)(Alo + (size_t)blockIdx.x * 64 * 128);
        const uint4* sh4 = (const uint4*)Wh;
        const uint4* sl4 = (const uint4*)Wl;
        for (int i = tid; i < 64 * 128 / 8; i += 256) {
            gh[i] = sh4[i];
            gl[i] = sl4[i];
        }
    }
    if (tid < 128) {
        atomicAdd(&ssum[tid], lsum[tid]);
        atomicAdd(&ssq [tid], lsq [tid]);
    }
}

// ---------------------------------------------------------------------------
// Fused level-2 pass over t4: computes BN-B coeffs from stats in prologue.
// Blocks [0,512) = parent2-sorted gather -> p2 (chunks 16, atomics);
// blocks [512,1024) = tree1-sorted accumulate+project -> acc1.
// ---------------------------------------------------------------------------
__global__ __launch_bounds__(512) void k_l2(
    const u16* __restrict__ shi, const u16* __restrict__ slo,
    const int* __restrict__ child2, const int* __restrict__ off2,
    const int* __restrict__ cnt2,
    const int* __restrict__ childT1, const int* __restrict__ offT1,
    const int* __restrict__ cntT1,
    const float* __restrict__ sumB, const float* __restrict__ sqB,
    const float* __restrict__ bng, const float* __restrict__ bnb,
    const float* __restrict__ predW,
    float* __restrict__ p2, float* __restrict__ acc1)
{
    __shared__ __align__(16) float scl[128], shl[128];
    const int tid = threadIdx.x;
    if (tid < 128) {
        float m = sumB[tid] * (1.f / N1c);
        float v = sqB[tid] * (1.f / N1c) - m * m;
        float s = bng[tid] * rsqrtf(v + EPSc);
        scl[tid] = s;
        shl[tid] = bnb[tid] - m * s;
    }
    __syncthreads();

    const int lane = tid & 31;
    const int sub  = tid >> 5;
    float4 sc4 = ((const float4*)scl)[lane];
    float4 sh4 = ((const float4*)shl)[lane];

    if (blockIdx.x < 512) {
        const int t = blockIdx.x * 16 + sub;      // 8192 tasks, 1 each
        const int seg = t % Bc;
        const int ch  = t / Bc;
        const int beg = off2[seg], len = cnt2[seg];
        int c0 = (int)(((long long)len * ch) / 16);
        int c1 = (int)(((long long)len * (ch + 1)) / 16);
        float4 acc = make_float4(0.f, 0.f, 0.f, 0.f);
        for (int c = c0; c < c1; ++c) {
            int r0 = child2[beg + c];
            ushort4 h = *(const ushort4*)(shi + (size_t)r0 * Hc + lane * 4);
            ushort4 lo = *(const ushort4*)(slo + (size_t)r0 * Hc + lane * 4);
            acc.x += fmaxf(fmaf(bf2f(h.x)+bf2f(lo.x), sc4.x, sh4.x), 0.f);
            acc.y += fmaxf(fmaf(bf2f(h.y)+bf2f(lo.y), sc4.y, sh4.y), 0.f);
            acc.z += fmaxf(fmaf(bf2f(h.z)+bf2f(lo.z), sc4.z, sh4.z), 0.f);
            acc.w += fmaxf(fmaf(bf2f(h.w)+bf2f(lo.w), sc4.w, sh4.w), 0.f);
        }
        float* d = p2 + (size_t)seg * Hc + lane * 4;
        atomicAdd(d + 0, acc.x);
        atomicAdd(d + 1, acc.y);
        atomicAdd(d + 2, acc.z);
        atomicAdd(d + 3, acc.w);
    } else {
        float4 wreg[Cc];
        #pragma unroll
        for (int cc = 0; cc < Cc; cc++) {
            wreg[cc].x = predW[(Hc + lane*4 + 0) * Cc + cc];
            wreg[cc].y = predW[(Hc + lane*4 + 1) * Cc + cc];
            wreg[cc].z = predW[(Hc + lane*4 + 2) * Cc + cc];
            wreg[cc].w = predW[(Hc + lane*4 + 3) * Cc + cc];
        }
        const int t = (blockIdx.x - 512) * 16 + sub;  // 8192 tasks
        const int tr = t & (Bc - 1);
        const int ch = t >> 9;
        const int beg = offT1[tr], len = cntT1[tr];
        int c0 = (int)(((long long)len * ch) / 16);
        int c1 = (int)(((long long)len * (ch + 1)) / 16);
        float4 acc = make_float4(0.f, 0.f, 0.f, 0.f);
        for (int c = c0; c < c1; ++c) {
            int r0 = childT1[beg + c];
            ushort4 h = *(const ushort4*)(shi + (size_t)r0 * Hc + lane * 4);
            ushort4 lo = *(const ushort4*)(slo + (size_t)r0 * Hc + lane * 4);
            acc.x += fmaxf(fmaf(bf2f(h.x)+bf2f(lo.x), sc4.x, sh4.x), 0.f);
            acc.y += fmaxf(fmaf(bf2f(h.y)+bf2f(lo.y), sc4.y, sh4.y), 0.f);
            acc.z += fmaxf(fmaf(bf2f(h.z)+bf2f(lo.z), sc4.z, sh4.z), 0.f);
            acc.w += fmaxf(fmaf(bf2f(h.w)+bf2f(lo.w), sc4.w, sh4.w), 0.f);
        }
        float pv[Cc];
        #pragma unroll
        for (int cc = 0; cc < Cc; cc++) {
            pv[cc] = acc.x * wreg[cc].x + acc.y * wreg[cc].y
                   + acc.z * wreg[cc].z + acc.w * wreg[cc].w;
        }
        #pragma unroll
        for (int o = 16; o; o >>= 1) {
            #pragma unroll
            for (int cc = 0; cc < Cc; cc++) pv[cc] += __shfl_xor(pv[cc], o, 32);
        }
        if (lane == 0) {
            #pragma unroll
            for (int cc = 0; cc < Cc; cc++) atomicAdd(&acc1[tr * Cc + cc], pv[cc]);
        }
    }
}

// ---------------------------------------------------------------------------
// fp32 GEMM for the tiny level-2 MLP; BN_IN=1 computes BN-C coeffs from
// stats in the prologue (invN = 1/Bc).
// ---------------------------------------------------------------------------
template<int BN_IN>
__global__ __launch_bounds__(256) void k_gemm2(
    const float* __restrict__ in, float* __restrict__ out,
    const float* __restrict__ W, const float* __restrict__ bias,
    const float* __restrict__ bn_sum, const float* __restrict__ bn_sq,
    const float* __restrict__ bn_g, const float* __restrict__ bn_b,
    float* __restrict__ ssum, float* __restrict__ ssq)
{
    __shared__ float Wlds[Hc * Hc];
    __shared__ float inl[32 * Hc];
    __shared__ __align__(16) float scl[128], shl[128];

    const int tid = threadIdx.x;
    if (BN_IN && tid < 128) {
        float m = bn_sum[tid] * (1.f / Bc);
        float v = bn_sq[tid] * (1.f / Bc) - m * m;
        float s = bn_g[tid] * rsqrtf(v + EPSc);
        scl[tid] = s;
        shl[tid] = bn_b[tid] - m * s;
    }
    {
        const float4* W4 = (const float4*)W;
        float4* Wl4 = (float4*)Wlds;
        for (int i = tid; i < Hc * Hc / 4; i += 256) Wl4[i] = W4[i];
    }
    __syncthreads();
    const int row0 = blockIdx.x * 32;
    for (int i = tid; i < 32 * 32; i += 256) {
        int r = i >> 5, g = i & 31;
        float4 v = ((const float4*)(in + (size_t)(row0 + r) * Hc))[g];
        if (BN_IN) {
            float4 sc = ((const float4*)scl)[g];
            float4 sh = ((const float4*)shl)[g];
            v.x = fmaxf(v.x * sc.x + sh.x, 0.f);
            v.y = fmaxf(v.y * sc.y + sh.y, 0.f);
            v.z = fmaxf(v.z * sc.z + sh.z, 0.f);
            v.w = fmaxf(v.w * sc.w + sh.w, 0.f);
        }
        ((float4*)(inl + r * Hc))[g] = v;
    }
    __syncthreads();

    const int rg = tid >> 5;
    const int cg = tid & 31;
    float acc[4][4] = {{0.f}};
    for (int k = 0; k < Hc; k += 4) {
        float a[4][4], w[4][4];
        #pragma unroll
        for (int r = 0; r < 4; r++) {
            float4 t = *(const float4*)&inl[(rg*4 + r) * Hc + k];
            a[r][0] = t.x; a[r][1] = t.y; a[r][2] = t.z; a[r][3] = t.w;
        }
        #pragma unroll
        for (int kk = 0; kk < 4; kk++) {
            float4 t = *(const float4*)&Wlds[(k + kk) * Hc + cg*4];
            w[kk][0] = t.x; w[kk][1] = t.y; w[kk][2] = t.z; w[kk][3] = t.w;
        }
        #pragma unroll
        for (int r = 0; r < 4; r++)
            #pragma unroll
            for (int kk = 0; kk < 4; kk++)
                #pragma unroll
                for (int c = 0; c < 4; c++)
                    acc[r][c] = fmaf(a[r][kk], w[kk][c], acc[r][c]);
    }

    float b4[4];
    #pragma unroll
    for (int c = 0; c < 4; c++) b4[c] = bias[cg*4 + c];
    float s[4] = {0.f,0.f,0.f,0.f}, q[4] = {0.f,0.f,0.f,0.f};
    #pragma unroll
    for (int r = 0; r < 4; r++) {
        float v0 = acc[r][0] + b4[0];
        float v1 = acc[r][1] + b4[1];
        float v2 = acc[r][2] + b4[2];
        float v3 = acc[r][3] + b4[3];
        float4 o; o.x = v0; o.y = v1; o.z = v2; o.w = v3;
        s[0] += v0; s[1] += v1; s[2] += v2; s[3] += v3;
        q[0] += v0*v0; q[1] += v1*v1; q[2] += v2*v2; q[3] += v3*v3;
        *(float4*)&out[(size_t)(row0 + rg*4 + r) * Hc + cg*4] = o;
    }

    __syncthreads();
    #pragma unroll
    for (int c = 0; c < 4; c++) inl[rg * Hc + cg*4 + c] = s[c];
    __syncthreads();
    if (tid < Hc) {
        float t = 0.f;
        #pragma unroll
        for (int g = 0; g < 8; g++) t += inl[g * Hc + tid];
        atomicAdd(&ssum[tid], t);
    }
    __syncthreads();
    #pragma unroll
    for (int c = 0; c < 4; c++) inl[rg * Hc + cg*4 + c] = q[c];
    __syncthreads();
    if (tid < Hc) {
        float t = 0.f;
        #pragma unroll
        for (int g = 0; g < 8; g++) t += inl[g * Hc + tid];
        atomicAdd(&ssq[tid], t);
    }
}

// ---------------------------------------------------------------------------
// Final: BN-D coeffs computed per-thread from stats; logits + softmax.
// ---------------------------------------------------------------------------
__global__ __launch_bounds__(128) void k_final(
    const float* __restrict__ u2,
    const float* __restrict__ sumD, const float* __restrict__ sqD,
    const float* __restrict__ bng, const float* __restrict__ bnb,
    const float* __restrict__ acc0, const float* __restrict__ acc1,
    const float* __restrict__ predW, const float* __restrict__ predb,
    float* __restrict__ out)
{
    __shared__ float h[Hc];
    __shared__ float wl[Hc * Cc];
    __shared__ float lg[Cc], ex[Cc];
    int b = blockIdx.x, t = threadIdx.x;
    for (int i = t; i < Hc * Cc; i += 128) wl[i] = predW[(2*Hc) * Cc + i];
    {
        float m = sumD[t] * (1.f / Bc);
        float v = sqD[t] * (1.f / Bc) - m * m;
        float s = bng[t] * rsqrtf(v + EPSc);
        float x = u2[(size_t)b * Hc + t];
        h[t] = fmaxf(x * s + (bnb[t] - m * s), 0.f);
    }
    __syncthreads();
    if (t < Cc) {
        float s = predb[t] + acc0[b * Cc + t] + acc1[b * Cc + t];
        for (int d = 0; d < Hc; d++) s += h[d] * wl[d * Cc + t];
        lg[t] = s;
    }
    __syncthreads();
    if (t < Cc) {
        float m = lg[0];
        #pragma unroll
        for (int c = 1; c < Cc; c++) m = fmaxf(m, lg[c]);
        ex[t] = expf(lg[t] - m);
    }
    __syncthreads();
    if (t < Cc) {
        float s = 0.f;
        #pragma unroll
        for (int c = 0; c < Cc; c++) s += ex[c];
        out[b * Cc + t] = ex[t] / s;
    }
}

extern "C" void kernel_launch(void* const* d_in, const int* in_sizes, int n_in,
                              void* d_out, int out_size, void* d_ws, size_t ws_size,
                              hipStream_t stream) {
    const float* h0      = (const float*)d_in[0];
    const int*   parent1 = (const int*)d_in[1];
    const int*   parent2 = (const int*)d_in[2];
    const int*   tree0   = (const int*)d_in[3];
    const int*   tree1   = (const int*)d_in[4];
    const float* m1W1 = (const float*)d_in[5];
    const float* m1b1 = (const float*)d_in[6];
    const float* m1bng = (const float*)d_in[7];
    const float* m1bnb = (const float*)d_in[8];
    const float* m1W2 = (const float*)d_in[9];
    const float* m1b2 = (const float*)d_in[10];
    const float* bn1g = (const float*)d_in[11];
    const float* bn1b = (const float*)d_in[12];
    const float* m2W1 = (const float*)d_in[13];
    const float* m2b1 = (const float*)d_in[14];
    const float* m2bng = (const float*)d_in[15];
    const float* m2bnb = (const float*)d_in[16];
    const float* m2W2 = (const float*)d_in[17];
    const float* m2b2 = (const float*)d_in[18];
    const float* bn2g = (const float*)d_in[19];
    const float* bn2b = (const float*)d_in[20];
    const float* predW = (const float*)d_in[21];
    const float* predb = (const float*)d_in[22];
    float* out = (float*)d_out;

    // ---- workspace layout ----
    u16* phi = (u16*)d_ws;                              // N1*128 u16 (p1->t1->t4 hi)
    u16* plo = phi + (size_t)N1c * Hc;                  // N1*128 u16 (lo)
    float* fbase = (float*)(plo + (size_t)N1c * Hc);
    float* p2    = fbase;                               // 512*128   (zeroed block start)
    float* acc0  = p2 + Bc * Hc;                        // 5120
    float* acc1  = acc0 + Bc * Cc;                      // 5120
    float* stats = acc1 + Bc * Cc;                      // 8*128     (zeroed block end)
    float* u1    = stats + 8 * Hc;                      // 512*128
    float* u2    = u1 + Bc * Hc;                        // 512*128
    int* ints   = (int*)(u2 + Bc * Hc);
    int* cnt1   = ints;                  // 131072  (zeroed: cnt1,off1,cur1)
    int* off1   = cnt1 + N1c;
    int* cur1   = off1 + N1c;
    int* cntT0  = cur1 + N1c;            // 512-bin block: 10*512 zeroed
    int* offT0  = cntT0 + Bc;
    int* curT0  = offT0 + Bc;
    int* cnt2   = curT0 + Bc;
    int* off2   = cnt2 + Bc;
    int* cur2   = off2 + Bc;
    int* cntT1  = cur2 + Bc;
    int* offT1  = cntT1 + Bc;
    int* curT1  = offT1 + Bc;
    int* bsum   = curT1 + Bc;
    int* child1 = bsum + Bc;             // 524288
    int* childT0= child1 + N0c;          // 524288
    int* child2 = childT0 + N0c;         // 131072
    int* childT1= child2 + N1c;          // 131072

    float* sumA = stats + 0 * Hc; float* sqA = stats + 1 * Hc;
    float* sumB = stats + 2 * Hc; float* sqB = stats + 3 * Hc;
    float* sumC = stats + 4 * Hc; float* sqC = stats + 5 * Hc;
    float* sumD = stats + 6 * Hc; float* sqD = stats + 7 * Hc;

    // ---- zero counters / accumulators (3 calls) ----
    hipMemsetAsync(cnt1, 0, 3 * (size_t)N1c * sizeof(int), stream);
    hipMemsetAsync(cntT0, 0, 10 * Bc * sizeof(int), stream);
    hipMemsetAsync(p2, 0, (size_t)(Bc * Hc + 2 * Bc * Cc + 8 * Hc) * sizeof(float), stream);

    // ---- counting sorts: 5 launches ----
    k_count_all<<<640, 256, 0, stream>>>(parent1, cnt1, tree0, cntT0,
                                         parent2, cnt2, tree1, cntT1);
    k_scan_local<<<N1c / 256, 256, 0, stream>>>(cnt1, off1, bsum, N1c);
    k_scan_sums4<<<4, 512, 0, stream>>>(bsum, cntT0, offT0, cnt2, off2, cntT1, offT1);
    k_scan_add<<<N1c / 256, 256, 0, stream>>>(off1, bsum, N1c);
    k_place_all<<<704, 1024, 0, stream>>>(parent1, off1, cur1, child1,
                                          tree0, offT0, curT0, childT0,
                                          parent2, off2, cur2, child2,
                                          tree1, offT1, curT1, childT1);

    // ---- level 1: fused gather(split-bf16) + g0 projection ----
    k_l1<<<5120, 512, 0, stream>>>(h0, child1, off1, cnt1, childT0, offT0, cntT0,
                                   predW, phi, plo, acc0);

    // ---- layer-1 MLP via split-bf16 MFMA (in place, BN folded) ----
    k_gemm_mfma<0><<<N1c / 64, 256, 0, stream>>>(phi, plo, m1W1, m1b1,
                                                 nullptr, nullptr, nullptr, nullptr,
                                                 0.f, sumA, sqA);
    k_gemm_mfma<1><<<N1c / 64, 256, 0, stream>>>(phi, plo, m1W2, m1b2,
                                                 sumA, sqA, m1bng, m1bnb,
                                                 1.f / N1c, sumB, sqB);

    // ---- level 2: fused gather + g1 projection (BN-B computed in-kernel) ----
    k_l2<<<1024, 512, 0, stream>>>(phi, plo, child2, off2, cnt2,
                                   childT1, offT1, cntT1,
                                   sumB, sqB, bn1g, bn1b, predW, p2, acc1);

    // ---- layer-2 MLP (BN folded) + final ----
    k_gemm2<0><<<Bc / 32, 256, 0, stream>>>(p2, u1, m2W1, m2b1,
                                            nullptr, nullptr, nullptr, nullptr,
                                            sumC, sqC);
    k_gemm2<1><<<Bc / 32, 256, 0, stream>>>(u1, u2, m2W2, m2b2,
                                            sumC, sqC, m2bng, m2bnb,
                                            sumD, sqD);
    k_final<<<Bc, 128, 0, stream>>>(u2, sumD, sqD, bn2g, bn2b,
                                    acc0, acc1, predW, predb, out);
}

// Round 7
// 378.680 us; speedup vs baseline: 3.8519x; 1.1780x over previous
//
#include <hip/hip_runtime.h>

#define N0c 524288
#define N1c 131072
#define Bc  512
#define Dc  128
#define Hc  128
#define Cc  10
#define EPSc 1e-5f
#define PB_CH 4096

typedef unsigned short u16;
typedef __attribute__((ext_vector_type(8))) short bf16x8;
typedef __attribute__((ext_vector_type(4))) float f32x4;

__device__ __forceinline__ u16 f2bf(float f) {
    unsigned u = __builtin_bit_cast(unsigned, f);
    unsigned r = (u + 0x7fffu + ((u >> 16) & 1u)) >> 16;
    return (u16)r;
}
__device__ __forceinline__ float bf2f(u16 h) {
    return __builtin_bit_cast(float, (unsigned)h << 16);
}

// ---------------------------------------------------------------------------
// Fused histograms.
// ---------------------------------------------------------------------------
__global__ __launch_bounds__(256) void k_count_all(
    const int* __restrict__ parent1, int* __restrict__ cnt1,
    const int* __restrict__ tree0, int* __restrict__ cntT0,
    const int* __restrict__ parent2, int* __restrict__ cnt2,
    const int* __restrict__ tree1, int* __restrict__ cntT1)
{
    __shared__ int hA[Bc], hB[Bc];
    const int b = blockIdx.x, tid = threadIdx.x;
    if (b < 512) {
        for (int i = tid; i < Bc; i += 256) hA[i] = 0;
        __syncthreads();
        for (int i = b * 256 + tid; i < N0c; i += 512 * 256) {
            atomicAdd(&cnt1[parent1[i]], 1);
            atomicAdd(&hA[tree0[i]], 1);
        }
        __syncthreads();
        for (int i = tid; i < Bc; i += 256) {
            int v = hA[i];
            if (v) atomicAdd(&cntT0[i], v);
        }
    } else {
        for (int i = tid; i < Bc; i += 256) { hA[i] = 0; hB[i] = 0; }
        __syncthreads();
        for (int i = (b - 512) * 256 + tid; i < N1c; i += 128 * 256) {
            atomicAdd(&hA[parent2[i]], 1);
            atomicAdd(&hB[tree1[i]], 1);
        }
        __syncthreads();
        for (int i = tid; i < Bc; i += 256) {
            int v = hA[i]; if (v) atomicAdd(&cnt2[i], v);
            v = hB[i];     if (v) atomicAdd(&cntT1[i], v);
        }
    }
}

__global__ __launch_bounds__(256) void k_scan_local(const int* __restrict__ cnt,
                                                    int* __restrict__ off,
                                                    int* __restrict__ bsum, int n)
{
    __shared__ int s[256];
    int t = threadIdx.x;
    int i = blockIdx.x * 256 + t;
    int v = (i < n) ? cnt[i] : 0;
    s[t] = v; __syncthreads();
    for (int o = 1; o < 256; o <<= 1) {
        int x = (t >= o) ? s[t - o] : 0;
        __syncthreads();
        s[t] += x;
        __syncthreads();
    }
    if (i < n) off[i] = s[t] - v;
    if (t == 255) bsum[blockIdx.x] = s[255];
}

// blocks 0-511: add prefix(bsum) to off1 slice; blocks 512-514: 512-bin scans.
__global__ __launch_bounds__(512) void k_scan_fin(
    const int* __restrict__ bsum, int* __restrict__ off1,
    const int* __restrict__ cntT0, int* __restrict__ offT0,
    const int* __restrict__ cnt2,  int* __restrict__ off2,
    const int* __restrict__ cntT1, int* __restrict__ offT1)
{
    __shared__ int s[512];
    const int t = threadIdx.x, b = blockIdx.x;
    if (b < 512) {
        s[t] = (t < b) ? bsum[t] : 0;
        __syncthreads();
        for (int o = 256; o; o >>= 1) {
            if (t < o) s[t] += s[t + o];
            __syncthreads();
        }
        int pre = s[0];
        if (t < 256) off1[b * 256 + t] += pre;
    } else {
        const int* src; int* dst;
        if (b == 512)      { src = cntT0; dst = offT0; }
        else if (b == 513) { src = cnt2;  dst = off2;  }
        else               { src = cntT1; dst = offT1; }
        int v = src[t];
        s[t] = v; __syncthreads();
        for (int o = 1; o < 512; o <<= 1) {
            int x = (t >= o) ? s[t - o] : 0;
            __syncthreads();
            s[t] += x;
            __syncthreads();
        }
        dst[t] = s[t] - v;
    }
}

// ---------------------------------------------------------------------------
// Fused placement.
// ---------------------------------------------------------------------------
__device__ __forceinline__ void place_binned(
    const int* __restrict__ idx, const int* __restrict__ off,
    int* __restrict__ cur, int* __restrict__ child, int n,
    int cb, int* h, int* base)
{
    const int tid = threadIdx.x;
    const int c0 = cb * PB_CH;
    const int c1 = min(c0 + PB_CH, n);
    for (int i = tid; i < Bc; i += 1024) h[i] = 0;
    __syncthreads();
    for (int i = c0 + tid; i < c1; i += 1024)
        atomicAdd(&h[idx[i]], 1);
    __syncthreads();
    for (int i = tid; i < Bc; i += 1024) {
        int v = h[i];
        base[i] = v ? atomicAdd(&cur[i], v) : 0;
    }
    __syncthreads();
    for (int i = tid; i < Bc; i += 1024) h[i] = 0;
    __syncthreads();
    for (int i = c0 + tid; i < c1; i += 1024) {
        int b = idx[i];
        int p = atomicAdd(&h[b], 1);
        child[off[b] + base[b] + p] = i;
    }
}

__global__ __launch_bounds__(1024) void k_place_all(
    const int* __restrict__ parent1, const int* __restrict__ off1,
    int* __restrict__ cur1, int* __restrict__ child1,
    const int* __restrict__ tree0, const int* __restrict__ offT0,
    int* __restrict__ curT0, int* __restrict__ childT0,
    const int* __restrict__ parent2, const int* __restrict__ off2,
    int* __restrict__ cur2, int* __restrict__ child2,
    const int* __restrict__ tree1, const int* __restrict__ offT1,
    int* __restrict__ curT1, int* __restrict__ childT1)
{
    __shared__ int h[Bc], base[Bc];
    const int b = blockIdx.x;
    if (b < 512) {
        int r = b * 1024 + threadIdx.x;   // 512*1024 == N0c exactly
        int p = parent1[r];
        int pos = off1[p] + atomicAdd(&cur1[p], 1);
        child1[pos] = r;
    } else if (b < 640) {
        place_binned(tree0, offT0, curT0, childT0, N0c, b - 512, h, base);
    } else if (b < 672) {
        place_binned(parent2, off2, cur2, child2, N1c, b - 640, h, base);
    } else {
        place_binned(tree1, offT1, curT1, childT1, N1c, b - 672, h, base);
    }
}

// ---------------------------------------------------------------------------
// Fused level-1 pass. Blocks [0,1024): tree-sorted accumulate+project (long
// tasks FIRST to avoid tail). Blocks [1024,5120): parent-sorted gather into
// split-bf16 p1. Both roles: lane-parallel index fetch + 8-deep row loads.
// ---------------------------------------------------------------------------
__global__ __launch_bounds__(512) void k_l1(
    const float* __restrict__ src,
    const int* __restrict__ child1, const int* __restrict__ off1,
    const int* __restrict__ cnt1,
    const int* __restrict__ childT0, const int* __restrict__ offT0,
    const int* __restrict__ cntT0,
    const float* __restrict__ predW,
    u16* __restrict__ dhi, u16* __restrict__ dlo, float* __restrict__ accOut)
{
    const int lane = threadIdx.x & 31;
    const int sub  = threadIdx.x >> 5;

    if (blockIdx.x >= 1024) {
        // ---- gather role: 65536 group-slots, 2 segments each ----
        const int slot = (blockIdx.x - 1024) * 16 + sub;
        #pragma unroll
        for (int rep = 0; rep < 2; rep++) {
            const int seg = slot + rep * 65536;
            const int beg = off1[seg], len = cnt1[seg];
            float4 acc = make_float4(0.f, 0.f, 0.f, 0.f);
            for (int c0 = 0; c0 < len; c0 += 8) {
                const int rem = len - c0;
                int idx = 0;
                if (lane < 8 && lane < rem) idx = child1[beg + c0 + lane];
                float4 v[8];
                #pragma unroll
                for (int j = 0; j < 8; j++) {
                    int r = __shfl(idx, j, 32);
                    v[j] = (j < rem)
                         ? ((const float4*)(src + (size_t)r * Hc))[lane]
                         : make_float4(0.f, 0.f, 0.f, 0.f);
                }
                acc.x += ((v[0].x+v[1].x)+(v[2].x+v[3].x)) + ((v[4].x+v[5].x)+(v[6].x+v[7].x));
                acc.y += ((v[0].y+v[1].y)+(v[2].y+v[3].y)) + ((v[4].y+v[5].y)+(v[6].y+v[7].y));
                acc.z += ((v[0].z+v[1].z)+(v[2].z+v[3].z)) + ((v[4].z+v[5].z)+(v[6].z+v[7].z));
                acc.w += ((v[0].w+v[1].w)+(v[2].w+v[3].w)) + ((v[4].w+v[5].w)+(v[6].w+v[7].w));
            }
            ushort4 hv, lv;
            hv.x = f2bf(acc.x); lv.x = f2bf(acc.x - bf2f(hv.x));
            hv.y = f2bf(acc.y); lv.y = f2bf(acc.y - bf2f(hv.y));
            hv.z = f2bf(acc.z); lv.z = f2bf(acc.z - bf2f(hv.z));
            hv.w = f2bf(acc.w); lv.w = f2bf(acc.w - bf2f(hv.w));
            *(ushort4*)(dhi + (size_t)seg * Hc + lane * 4) = hv;
            *(ushort4*)(dlo + (size_t)seg * Hc + lane * 4) = lv;
        }
    } else {
        // ---- projection role: 32768 tasks (chunks=64), 2 per group ----
        const int slot = blockIdx.x * 16 + sub;
        #pragma unroll
        for (int rep = 0; rep < 2; rep++) {
            const int t  = slot + rep * 16384;
            const int tr = t & (Bc - 1);
            const int ch = t >> 9;                      // 0..63
            const int beg = offT0[tr], len = cntT0[tr];
            const int c0 = (int)(((long long)len * ch) >> 6);
            const int c1 = (int)(((long long)len * (ch + 1)) >> 6);
            if (c0 >= c1) continue;
            float4 acc = make_float4(0.f, 0.f, 0.f, 0.f);
            for (int c = c0; c < c1; c += 8) {
                const int rem = c1 - c;
                int idx = 0;
                if (lane < 8 && lane < rem) idx = childT0[beg + c + lane];
                float4 v[8];
                #pragma unroll
                for (int j = 0; j < 8; j++) {
                    int r = __shfl(idx, j, 32);
                    v[j] = (j < rem)
                         ? ((const float4*)(src + (size_t)r * Hc))[lane]
                         : make_float4(0.f, 0.f, 0.f, 0.f);
                }
                acc.x += ((v[0].x+v[1].x)+(v[2].x+v[3].x)) + ((v[4].x+v[5].x)+(v[6].x+v[7].x));
                acc.y += ((v[0].y+v[1].y)+(v[2].y+v[3].y)) + ((v[4].y+v[5].y)+(v[6].y+v[7].y));
                acc.z += ((v[0].z+v[1].z)+(v[2].z+v[3].z)) + ((v[4].z+v[5].z)+(v[6].z+v[7].z));
                acc.w += ((v[0].w+v[1].w)+(v[2].w+v[3].w)) + ((v[4].w+v[5].w)+(v[6].w+v[7].w));
            }
            // project once per task; wreg loaded here (short live range, L2-hot)
            float pv[Cc];
            #pragma unroll
            for (int cc = 0; cc < Cc; cc++) {
                float w0 = predW[(lane*4 + 0) * Cc + cc];
                float w1 = predW[(lane*4 + 1) * Cc + cc];
                float w2 = predW[(lane*4 + 2) * Cc + cc];
                float w3 = predW[(lane*4 + 3) * Cc + cc];
                pv[cc] = acc.x * w0 + acc.y * w1 + acc.z * w2 + acc.w * w3;
            }
            #pragma unroll
            for (int o = 16; o; o >>= 1) {
                #pragma unroll
                for (int cc = 0; cc < Cc; cc++) pv[cc] += __shfl_xor(pv[cc], o, 32);
            }
            if (lane == 0) {
                #pragma unroll
                for (int cc = 0; cc < Cc; cc++) atomicAdd(&accOut[tr * Cc + cc], pv[cc]);
            }
        }
    }
}

// ---------------------------------------------------------------------------
// Split-bf16 MFMA GEMM, 128 rows/block (512 thr, 8 waves), in place.
// ---------------------------------------------------------------------------
template<int BN_IN>
__global__ __launch_bounds__(512) void k_gemm_mfma(
    u16* __restrict__ Ahi, u16* __restrict__ Alo,
    const float* __restrict__ W, const float* __restrict__ bias,
    const float* __restrict__ bn_sum, const float* __restrict__ bn_sq,
    const float* __restrict__ bn_g, const float* __restrict__ bn_b, float invN,
    float* __restrict__ ssum, float* __restrict__ ssq)
{
    __shared__ __align__(16) u16 Wh[128 * 136];   // [n][k] transposed, padded
    __shared__ __align__(16) u16 Wl[128 * 136];
    __shared__ float bl[128], scl[128], shl[128];
    __shared__ float lsum[128], lsq[128];

    const int tid = threadIdx.x;
    for (int i = tid; i < 128 * 128; i += 512) {
        int k = i >> 7, n = i & 127;
        float f = W[i];
        u16 h = f2bf(f);
        Wh[n * 136 + k] = h;
        Wl[n * 136 + k] = f2bf(f - bf2f(h));
    }
    if (tid < 128) {
        bl[tid] = bias[tid];
        lsum[tid] = 0.f; lsq[tid] = 0.f;
        if (BN_IN) {
            float m = bn_sum[tid] * invN;
            float v = bn_sq[tid] * invN - m * m;
            float s = bn_g[tid] * rsqrtf(v + EPSc);
            scl[tid] = s;
            shl[tid] = bn_b[tid] - m * s;
        }
    }
    __syncthreads();

    const int wave = tid >> 6;          // 0..7
    const int l    = tid & 63;
    const int r16  = l & 15;
    const int kg   = l >> 4;
    const int row0 = blockIdx.x * 128 + wave * 16;

    const u16* arow_h = Ahi + (size_t)(row0 + r16) * 128 + kg * 8;
    const u16* arow_l = Alo + (size_t)(row0 + r16) * 128 + kg * 8;

    f32x4 acc[8];
    #pragma unroll
    for (int nt = 0; nt < 8; nt++) acc[nt] = (f32x4){0.f, 0.f, 0.f, 0.f};

    #pragma unroll
    for (int kk = 0; kk < 4; kk++) {
        bf16x8 ah, al;
        bf16x8 rh = *(const bf16x8*)(arow_h + kk * 32);
        bf16x8 rl = *(const bf16x8*)(arow_l + kk * 32);
        if (BN_IN == 0) {
            ah = rh; al = rl;
        } else {
            const int kb = kk * 32 + kg * 8;
            #pragma unroll
            for (int j = 0; j < 8; j++) {
                float x = bf2f((u16)rh[j]) + bf2f((u16)rl[j]);
                float y = fmaxf(fmaf(x, scl[kb + j], shl[kb + j]), 0.f);
                u16 yh = f2bf(y);
                ah[j] = (short)yh;
                al[j] = (short)f2bf(y - bf2f(yh));
            }
        }
        #pragma unroll
        for (int nt = 0; nt < 8; nt++) {
            const int bo = (nt * 16 + r16) * 136 + kk * 32 + kg * 8;
            bf16x8 bh = *(const bf16x8*)(Wh + bo);
            bf16x8 bw = *(const bf16x8*)(Wl + bo);
            acc[nt] = __builtin_amdgcn_mfma_f32_16x16x32_bf16(ah, bh, acc[nt], 0, 0, 0);
            acc[nt] = __builtin_amdgcn_mfma_f32_16x16x32_bf16(ah, bw, acc[nt], 0, 0, 0);
            acc[nt] = __builtin_amdgcn_mfma_f32_16x16x32_bf16(al, bh, acc[nt], 0, 0, 0);
        }
    }

    // epilogue: bias + stats (C/D layout: col = l&15, row = (l>>4)*4 + j)
    float v[8][4];
    #pragma unroll
    for (int nt = 0; nt < 8; nt++) {
        float b = bl[nt * 16 + r16];
        float s = 0.f, q = 0.f;
        #pragma unroll
        for (int j = 0; j < 4; j++) {
            float x = acc[nt][j] + b;
            v[nt][j] = x;
            s += x; q += x * x;
        }
        s += __shfl_xor(s, 16); s += __shfl_xor(s, 32);
        q += __shfl_xor(q, 16); q += __shfl_xor(q, 32);
        if (kg == 0) {
            atomicAdd(&lsum[nt * 16 + r16], s);
            atomicAdd(&lsq [nt * 16 + r16], q);
        }
    }
    __syncthreads();                 // all waves done reading Wh/Wl
    #pragma unroll
    for (int nt = 0; nt < 8; nt++) {
        #pragma unroll
        for (int j = 0; j < 4; j++) {
            int rl_ = wave * 16 + kg * 4 + j;     // 0..127
            int c   = nt * 16 + r16;
            float x = v[nt][j];
            u16 hh = f2bf(x);
            Wh[rl_ * 128 + c] = hh;
            Wl[rl_ * 128 + c] = f2bf(x - bf2f(hh));
        }
    }
    __syncthreads();
    {
        uint4* gh = (uint4*)(Ahi + (size_t)blockIdx.x * 128 * 128);
        uint4* gl = (uint4*)(Alo + (size_t)blockIdx.x * 128 * 128);
        const uint4* sh4 = (const uint4*)Wh;
        const uint4* sl4 = (const uint4*)Wl;
        for (int i = tid; i < 128 * 128 / 8; i += 512) {
            gh[i] = sh4[i];
            gl[i] = sl4[i];
        }
    }
    if (tid < 128) {
        atomicAdd(&ssum[tid], lsum[tid]);
        atomicAdd(&ssq [tid], lsq [tid]);
    }
}

// ---------------------------------------------------------------------------
// Fused level-2 pass over t4 (BN-B computed in prologue).
// ---------------------------------------------------------------------------
__global__ __launch_bounds__(512) void k_l2(
    const u16* __restrict__ shi, const u16* __restrict__ slo,
    const int* __restrict__ child2, const int* __restrict__ off2,
    const int* __restrict__ cnt2,
    const int* __restrict__ childT1, const int* __restrict__ offT1,
    const int* __restrict__ cntT1,
    const float* __restrict__ sumB, const float* __restrict__ sqB,
    const float* __restrict__ bng, const float* __restrict__ bnb,
    const float* __restrict__ predW,
    float* __restrict__ p2, float* __restrict__ acc1)
{
    __shared__ __align__(16) float scl[128], shl[128];
    const int tid = threadIdx.x;
    if (tid < 128) {
        float m = sumB[tid] * (1.f / N1c);
        float v = sqB[tid] * (1.f / N1c) - m * m;
        float s = bng[tid] * rsqrtf(v + EPSc);
        scl[tid] = s;
        shl[tid] = bnb[tid] - m * s;
    }
    __syncthreads();

    const int lane = tid & 31;
    const int sub  = tid >> 5;
    float4 sc4 = ((const float4*)scl)[lane];
    float4 sh4 = ((const float4*)shl)[lane];

    if (blockIdx.x < 512) {
        const int t = blockIdx.x * 16 + sub;      // 8192 tasks, 1 each
        const int seg = t % Bc;
        const int ch  = t / Bc;
        const int beg = off2[seg], len = cnt2[seg];
        int c0 = (int)(((long long)len * ch) / 16);
        int c1 = (int)(((long long)len * (ch + 1)) / 16);
        float4 acc = make_float4(0.f, 0.f, 0.f, 0.f);
        for (int c = c0; c < c1; ++c) {
            int r0 = child2[beg + c];
            ushort4 h = *(const ushort4*)(shi + (size_t)r0 * Hc + lane * 4);
            ushort4 lo = *(const ushort4*)(slo + (size_t)r0 * Hc + lane * 4);
            acc.x += fmaxf(fmaf(bf2f(h.x)+bf2f(lo.x), sc4.x, sh4.x), 0.f);
            acc.y += fmaxf(fmaf(bf2f(h.y)+bf2f(lo.y), sc4.y, sh4.y), 0.f);
            acc.z += fmaxf(fmaf(bf2f(h.z)+bf2f(lo.z), sc4.z, sh4.z), 0.f);
            acc.w += fmaxf(fmaf(bf2f(h.w)+bf2f(lo.w), sc4.w, sh4.w), 0.f);
        }
        float* d = p2 + (size_t)seg * Hc + lane * 4;
        atomicAdd(d + 0, acc.x);
        atomicAdd(d + 1, acc.y);
        atomicAdd(d + 2, acc.z);
        atomicAdd(d + 3, acc.w);
    } else {
        float4 wreg[Cc];
        #pragma unroll
        for (int cc = 0; cc < Cc; cc++) {
            wreg[cc].x = predW[(Hc + lane*4 + 0) * Cc + cc];
            wreg[cc].y = predW[(Hc + lane*4 + 1) * Cc + cc];
            wreg[cc].z = predW[(Hc + lane*4 + 2) * Cc + cc];
            wreg[cc].w = predW[(Hc + lane*4 + 3) * Cc + cc];
        }
        const int t = (blockIdx.x - 512) * 16 + sub;  // 8192 tasks
        const int tr = t & (Bc - 1);
        const int ch = t >> 9;
        const int beg = offT1[tr], len = cntT1[tr];
        int c0 = (int)(((long long)len * ch) / 16);
        int c1 = (int)(((long long)len * (ch + 1)) / 16);
        float4 acc = make_float4(0.f, 0.f, 0.f, 0.f);
        for (int c = c0; c < c1; ++c) {
            int r0 = childT1[beg + c];
            ushort4 h = *(const ushort4*)(shi + (size_t)r0 * Hc + lane * 4);
            ushort4 lo = *(const ushort4*)(slo + (size_t)r0 * Hc + lane * 4);
            acc.x += fmaxf(fmaf(bf2f(h.x)+bf2f(lo.x), sc4.x, sh4.x), 0.f);
            acc.y += fmaxf(fmaf(bf2f(h.y)+bf2f(lo.y), sc4.y, sh4.y), 0.f);
            acc.z += fmaxf(fmaf(bf2f(h.z)+bf2f(lo.z), sc4.z, sh4.z), 0.f);
            acc.w += fmaxf(fmaf(bf2f(h.w)+bf2f(lo.w), sc4.w, sh4.w), 0.f);
        }
        float pv[Cc];
        #pragma unroll
        for (int cc = 0; cc < Cc; cc++) {
            pv[cc] = acc.x * wreg[cc].x + acc.y * wreg[cc].y
                   + acc.z * wreg[cc].z + acc.w * wreg[cc].w;
        }
        #pragma unroll
        for (int o = 16; o; o >>= 1) {
            #pragma unroll
            for (int cc = 0; cc < Cc; cc++) pv[cc] += __shfl_xor(pv[cc], o, 32);
        }
        if (lane == 0) {
            #pragma unroll
            for (int cc = 0; cc < Cc; cc++) atomicAdd(&acc1[tr * Cc + cc], pv[cc]);
        }
    }
}

// ---------------------------------------------------------------------------
// fp32 GEMM for the tiny level-2 MLP (BN folded when BN_IN=1).
// ---------------------------------------------------------------------------
template<int BN_IN>
__global__ __launch_bounds__(256) void k_gemm2(
    const float* __restrict__ in, float* __restrict__ out,
    const float* __restrict__ W, const float* __restrict__ bias,
    const float* __restrict__ bn_sum, const float* __restrict__ bn_sq,
    const float* __restrict__ bn_g, const float* __restrict__ bn_b,
    float* __restrict__ ssum, float* __restrict__ ssq)
{
    __shared__ float Wlds[Hc * Hc];
    __shared__ float inl[32 * Hc];
    __shared__ __align__(16) float scl[128], shl[128];

    const int tid = threadIdx.x;
    if (BN_IN && tid < 128) {
        float m = bn_sum[tid] * (1.f / Bc);
        float v = bn_sq[tid] * (1.f / Bc) - m * m;
        float s = bn_g[tid] * rsqrtf(v + EPSc);
        scl[tid] = s;
        shl[tid] = bn_b[tid] - m * s;
    }
    {
        const float4* W4 = (const float4*)W;
        float4* Wl4 = (float4*)Wlds;
        for (int i = tid; i < Hc * Hc / 4; i += 256) Wl4[i] = W4[i];
    }
    __syncthreads();
    const int row0 = blockIdx.x * 32;
    for (int i = tid; i < 32 * 32; i += 256) {
        int r = i >> 5, g = i & 31;
        float4 v = ((const float4*)(in + (size_t)(row0 + r) * Hc))[g];
        if (BN_IN) {
            float4 sc = ((const float4*)scl)[g];
            float4 sh = ((const float4*)shl)[g];
            v.x = fmaxf(v.x * sc.x + sh.x, 0.f);
            v.y = fmaxf(v.y * sc.y + sh.y, 0.f);
            v.z = fmaxf(v.z * sc.z + sh.z, 0.f);
            v.w = fmaxf(v.w * sc.w + sh.w, 0.f);
        }
        ((float4*)(inl + r * Hc))[g] = v;
    }
    __syncthreads();

    const int rg = tid >> 5;
    const int cg = tid & 31;
    float acc[4][4] = {{0.f}};
    for (int k = 0; k < Hc; k += 4) {
        float a[4][4], w[4][4];
        #pragma unroll
        for (int r = 0; r < 4; r++) {
            float4 t = *(const float4*)&inl[(rg*4 + r) * Hc + k];
            a[r][0] = t.x; a[r][1] = t.y; a[r][2] = t.z; a[r][3] = t.w;
        }
        #pragma unroll
        for (int kk = 0; kk < 4; kk++) {
            float4 t = *(const float4*)&Wlds[(k + kk) * Hc + cg*4];
            w[kk][0] = t.x; w[kk][1] = t.y; w[kk][2] = t.z; w[kk][3] = t.w;
        }
        #pragma unroll
        for (int r = 0; r < 4; r++)
            #pragma unroll
            for (int kk = 0; kk < 4; kk++)
                #pragma unroll
                for (int c = 0; c < 4; c++)
                    acc[r][c] = fmaf(a[r][kk], w[kk][c], acc[r][c]);
    }

    float b4[4];
    #pragma unroll
    for (int c = 0; c < 4; c++) b4[c] = bias[cg*4 + c];
    float s[4] = {0.f,0.f,0.f,0.f}, q[4] = {0.f,0.f,0.f,0.f};
    #pragma unroll
    for (int r = 0; r < 4; r++) {
        float v0 = acc[r][0] + b4[0];
        float v1 = acc[r][1] + b4[1];
        float v2 = acc[r][2] + b4[2];
        float v3 = acc[r][3] + b4[3];
        float4 o; o.x = v0; o.y = v1; o.z = v2; o.w = v3;
        s[0] += v0; s[1] += v1; s[2] += v2; s[3] += v3;
        q[0] += v0*v0; q[1] += v1*v1; q[2] += v2*v2; q[3] += v3*v3;
        *(float4*)&out[(size_t)(row0 + rg*4 + r) * Hc + cg*4] = o;
    }

    __syncthreads();
    #pragma unroll
    for (int c = 0; c < 4; c++) inl[rg * Hc + cg*4 + c] = s[c];
    __syncthreads();
    if (tid < Hc) {
        float t = 0.f;
        #pragma unroll
        for (int g = 0; g < 8; g++) t += inl[g * Hc + tid];
        atomicAdd(&ssum[tid], t);
    }
    __syncthreads();
    #pragma unroll
    for (int c = 0; c < 4; c++) inl[rg * Hc + cg*4 + c] = q[c];
    __syncthreads();
    if (tid < Hc) {
        float t = 0.f;
        #pragma unroll
        for (int g = 0; g < 8; g++) t += inl[g * Hc + tid];
        atomicAdd(&ssq[tid], t);
    }
}

// ---------------------------------------------------------------------------
// Final: BN-D coeffs from stats; logits + softmax.
// ---------------------------------------------------------------------------
__global__ __launch_bounds__(128) void k_final(
    const float* __restrict__ u2,
    const float* __restrict__ sumD, const float* __restrict__ sqD,
    const float* __restrict__ bng, const float* __restrict__ bnb,
    const float* __restrict__ acc0, const float* __restrict__ acc1,
    const float* __restrict__ predW, const float* __restrict__ predb,
    float* __restrict__ out)
{
    __shared__ float h[Hc];
    __shared__ float wl[Hc * Cc];
    __shared__ float lg[Cc], ex[Cc];
    int b = blockIdx.x, t = threadIdx.x;
    for (int i = t; i < Hc * Cc; i += 128) wl[i] = predW[(2*Hc) * Cc + i];
    {
        float m = sumD[t] * (1.f / Bc);
        float v = sqD[t] * (1.f / Bc) - m * m;
        float s = bng[t] * rsqrtf(v + EPSc);
        float x = u2[(size_t)b * Hc + t];
        h[t] = fmaxf(x * s + (bnb[t] - m * s), 0.f);
    }
    __syncthreads();
    if (t < Cc) {
        float s = predb[t] + acc0[b * Cc + t] + acc1[b * Cc + t];
        for (int d = 0; d < Hc; d++) s += h[d] * wl[d * Cc + t];
        lg[t] = s;
    }
    __syncthreads();
    if (t < Cc) {
        float m = lg[0];
        #pragma unroll
        for (int c = 1; c < Cc; c++) m = fmaxf(m, lg[c]);
        ex[t] = expf(lg[t] - m);
    }
    __syncthreads();
    if (t < Cc) {
        float s = 0.f;
        #pragma unroll
        for (int c = 0; c < Cc; c++) s += ex[c];
        out[b * Cc + t] = ex[t] / s;
    }
}

extern "C" void kernel_launch(void* const* d_in, const int* in_sizes, int n_in,
                              void* d_out, int out_size, void* d_ws, size_t ws_size,
                              hipStream_t stream) {
    const float* h0      = (const float*)d_in[0];
    const int*   parent1 = (const int*)d_in[1];
    const int*   parent2 = (const int*)d_in[2];
    const int*   tree0   = (const int*)d_in[3];
    const int*   tree1   = (const int*)d_in[4];
    const float* m1W1 = (const float*)d_in[5];
    const float* m1b1 = (const float*)d_in[6];
    const float* m1bng = (const float*)d_in[7];
    const float* m1bnb = (const float*)d_in[8];
    const float* m1W2 = (const float*)d_in[9];
    const float* m1b2 = (const float*)d_in[10];
    const float* bn1g = (const float*)d_in[11];
    const float* bn1b = (const float*)d_in[12];
    const float* m2W1 = (const float*)d_in[13];
    const float* m2b1 = (const float*)d_in[14];
    const float* m2bng = (const float*)d_in[15];
    const float* m2bnb = (const float*)d_in[16];
    const float* m2W2 = (const float*)d_in[17];
    const float* m2b2 = (const float*)d_in[18];
    const float* bn2g = (const float*)d_in[19];
    const float* bn2b = (const float*)d_in[20];
    const float* predW = (const float*)d_in[21];
    const float* predb = (const float*)d_in[22];
    float* out = (float*)d_out;

    // ---- workspace layout: ONE contiguous zero region ----
    u16* phi = (u16*)d_ws;                              // N1*128 u16
    u16* plo = phi + (size_t)N1c * Hc;                  // N1*128 u16
    float* zbase = (float*)(plo + (size_t)N1c * Hc);
    float* p2    = zbase;                               // 512*128
    float* acc0  = p2 + Bc * Hc;                        // 5120
    float* acc1  = acc0 + Bc * Cc;                      // 5120
    float* stats = acc1 + Bc * Cc;                      // 8*128
    int* cnt1   = (int*)(stats + 8 * Hc);               // 131072
    int* cur1   = cnt1 + N1c;                           // 131072
    int* cntT0  = cur1 + N1c;                           // 9*512 bins
    int* offT0  = cntT0 + Bc;
    int* curT0  = offT0 + Bc;
    int* cnt2   = curT0 + Bc;
    int* off2   = cnt2 + Bc;
    int* cur2   = off2 + Bc;
    int* cntT1  = cur2 + Bc;
    int* offT1  = cntT1 + Bc;
    int* curT1  = offT1 + Bc;
    // --- end of zero region ---
    int* zend   = curT1 + Bc;
    int* off1   = zend;                  // 131072 (written by scan)
    int* bsum   = off1 + N1c;            // 512
    int* child1 = bsum + Bc;             // 524288
    int* childT0= child1 + N0c;          // 524288
    int* child2 = childT0 + N0c;         // 131072
    int* childT1= child2 + N1c;          // 131072
    float* u1   = (float*)(childT1 + N1c);              // 512*128
    float* u2   = u1 + Bc * Hc;                         // 512*128

    float* sumA = stats + 0 * Hc; float* sqA = stats + 1 * Hc;
    float* sumB = stats + 2 * Hc; float* sqB = stats + 3 * Hc;
    float* sumC = stats + 4 * Hc; float* sqC = stats + 5 * Hc;
    float* sumD = stats + 6 * Hc; float* sqD = stats + 7 * Hc;

    const size_t zero_bytes = (char*)zend - (char*)zbase;
    hipMemsetAsync(zbase, 0, zero_bytes, stream);

    // ---- counting sorts: 4 launches ----
    k_count_all<<<640, 256, 0, stream>>>(parent1, cnt1, tree0, cntT0,
                                         parent2, cnt2, tree1, cntT1);
    k_scan_local<<<N1c / 256, 256, 0, stream>>>(cnt1, off1, bsum, N1c);
    k_scan_fin<<<515, 512, 0, stream>>>(bsum, off1, cntT0, offT0,
                                        cnt2, off2, cntT1, offT1);
    k_place_all<<<704, 1024, 0, stream>>>(parent1, off1, cur1, child1,
                                          tree0, offT0, curT0, childT0,
                                          parent2, off2, cur2, child2,
                                          tree1, offT1, curT1, childT1);

    // ---- level 1: fused proj(first) + gather(split-bf16) ----
    k_l1<<<5120, 512, 0, stream>>>(h0, child1, off1, cnt1, childT0, offT0, cntT0,
                                   predW, phi, plo, acc0);

    // ---- layer-1 MLP via split-bf16 MFMA (in place, BN folded) ----
    k_gemm_mfma<0><<<N1c / 128, 512, 0, stream>>>(phi, plo, m1W1, m1b1,
                                                  nullptr, nullptr, nullptr, nullptr,
                                                  0.f, sumA, sqA);
    k_gemm_mfma<1><<<N1c / 128, 512, 0, stream>>>(phi, plo, m1W2, m1b2,
                                                  sumA, sqA, m1bng, m1bnb,
                                                  1.f / N1c, sumB, sqB);

    // ---- level 2: fused gather + g1 projection ----
    k_l2<<<1024, 512, 0, stream>>>(phi, plo, child2, off2, cnt2,
                                   childT1, offT1, cntT1,
                                   sumB, sqB, bn1g, bn1b, predW, p2, acc1);

    // ---- layer-2 MLP (BN folded) + final ----
    k_gemm2<0><<<Bc / 32, 256, 0, stream>>>(p2, u1, m2W1, m2b1,
                                            nullptr, nullptr, nullptr, nullptr,
                                            sumC, sqC);
    k_gemm2<1><<<Bc / 32, 256, 0, stream>>>(u1, u2, m2W2, m2b2,
                                            sumC, sqC, m2bng, m2bnb,
                                            sumD, sqD);
    k_final<<<Bc, 128, 0, stream>>>(u2, sumD, sqD, bn2g, bn2b,
                                    acc0, acc1, predW, predb, out);
}